// Round 1
// baseline (1163.704 us; speedup 1.0000x reference)
//
#include <hip/hip_runtime.h>

// ChebyshevGCNN: out = relu(bias + x@W0 + T1@W1 + T2@W2 + T3@W3)
//   T1 = L x ; T2 = 2 L T1 - x ; T3 = 2 L T2 - T1   (L sparse, E edges, scatter rows / gather cols)
// Strategy: build CSR (grouped by destination row) per call, then gather-based SpMM
// (no float atomics), plus two fused dense GEMM passes with weights in LDS.

#define N_NODES 50000
#define N_EDGES 800000
#define BATCH 4
#define CH 64
#define BN (N_NODES * CH)             // elems per batch matrix = 3,200,000
#define ROWS_TOTAL (BATCH * N_NODES)  // 200,000

__global__ void hist_kernel(const int* __restrict__ rows, int* __restrict__ counts) {
  int e = blockIdx.x * blockDim.x + threadIdx.x;
  if (e < N_EDGES) atomicAdd(&counts[rows[e]], 1);
}

// Single-block exclusive scan over N_NODES counts -> row_start[N+1], cursor[N]
__global__ void scan_kernel(const int* __restrict__ counts,
                            int* __restrict__ row_start,
                            int* __restrict__ cursor) {
  __shared__ int sums[1024];
  int tid = threadIdx.x;
  const int per = (N_NODES + 1023) / 1024;  // 49
  int begin = tid * per;
  int end = begin + per; if (end > N_NODES) end = N_NODES;
  int s = 0;
  for (int i = begin; i < end; ++i) s += counts[i];
  sums[tid] = s;
  __syncthreads();
  // Hillis-Steele inclusive scan
  for (int off = 1; off < 1024; off <<= 1) {
    int t = (tid >= off) ? sums[tid - off] : 0;
    __syncthreads();
    sums[tid] += t;
    __syncthreads();
  }
  int running = sums[tid] - s;  // exclusive prefix
  for (int i = begin; i < end; ++i) {
    row_start[i] = running;
    cursor[i] = running;
    running += counts[i];
  }
  if (tid == 0) row_start[N_NODES] = N_EDGES;
}

__global__ void fill_kernel(const int* __restrict__ rows, const int* __restrict__ cols,
                            const float* __restrict__ vals, int* cursor,
                            int* __restrict__ cols_s, float* __restrict__ vals_s) {
  int e = blockIdx.x * blockDim.x + threadIdx.x;
  if (e >= N_EDGES) return;
  int r = rows[e];
  int pos = atomicAdd(&cursor[r], 1);
  cols_s[pos] = cols[e];
  vals_s[pos] = vals[e];
}

// dst[b][row][:] = alpha * sum_{edges of row} val * src[b][col][:]  - sub[b][row][:]
// 16 threads per row (4 channels each, float4), 4 batches looped in registers.
// NOTE: sub/dst may alias (T3 pass) -> no __restrict__ on them; each element is
// read and written by exactly one thread, read-then-write within the thread.
__global__ void spmm_csr(const int* __restrict__ row_start,
                         const int* __restrict__ cols_s,
                         const float* __restrict__ vals_s,
                         const float* __restrict__ src,
                         const float* sub,  // nullable
                         float* dst,
                         float alpha) {
  int g = blockIdx.x * blockDim.x + threadIdx.x;
  int row = g >> 4;
  if (row >= N_NODES) return;
  int c = (g & 15) << 2;  // channel offset: 0,4,...,60
  int s = row_start[row], e = row_start[row + 1];
  float acc[BATCH][4];
#pragma unroll
  for (int b = 0; b < BATCH; ++b) {
    acc[b][0] = 0.f; acc[b][1] = 0.f; acc[b][2] = 0.f; acc[b][3] = 0.f;
  }
  for (int i = s; i < e; ++i) {
    int col = cols_s[i];
    float v = vals_s[i];
    const float* p = src + col * CH + c;
#pragma unroll
    for (int b = 0; b < BATCH; ++b) {
      float4 sv = *reinterpret_cast<const float4*>(p + b * BN);
      acc[b][0] = fmaf(v, sv.x, acc[b][0]);
      acc[b][1] = fmaf(v, sv.y, acc[b][1]);
      acc[b][2] = fmaf(v, sv.z, acc[b][2]);
      acc[b][3] = fmaf(v, sv.w, acc[b][3]);
    }
  }
#pragma unroll
  for (int b = 0; b < BATCH; ++b) {
    int idx = b * BN + row * CH + c;
    float4 r;
    r.x = alpha * acc[b][0];
    r.y = alpha * acc[b][1];
    r.z = alpha * acc[b][2];
    r.w = alpha * acc[b][3];
    if (sub) {
      float4 sv = *reinterpret_cast<const float4*>(sub + idx);
      r.x -= sv.x; r.y -= sv.y; r.z -= sv.z; r.w -= sv.w;
    }
    *reinterpret_cast<float4*>(dst + idx) = r;
  }
}

// out[r][o] (+)= Ta[r][:]@Wa[:, o] + Tb[r][:]@Wb[:, o]  (+bias, relu if finalize)
// One wave per row-slice: lane = output channel o; weights staged in LDS.
__global__ __launch_bounds__(256) void gemm2_kernel(
    const float* __restrict__ Ta, const float* __restrict__ Tb,
    const float* __restrict__ Wa, const float* __restrict__ Wb,
    const float* __restrict__ bias, float* out,
    int accumulate, int finalize) {
  __shared__ float WA[64][64];
  __shared__ float WB[64][64];
  __shared__ float bias_s[64];
  for (int i = threadIdx.x; i < 64 * 64; i += 256) {
    WA[i >> 6][i & 63] = Wa[i];
    WB[i >> 6][i & 63] = Wb[i];
  }
  if (finalize && threadIdx.x < 64) bias_s[threadIdx.x] = bias[threadIdx.x];
  __syncthreads();
  int o = threadIdx.x & 63;
  int wid = threadIdx.x >> 6;
  int base = blockIdx.x * 64;
  for (int rr = wid; rr < 64; rr += 4) {
    int r = base + rr;
    const float* ta = Ta + r * 64;
    const float* tb = Tb + r * 64;
    float a = 0.f;
#pragma unroll
    for (int cc = 0; cc < 64; cc += 4) {
      float4 va = *reinterpret_cast<const float4*>(ta + cc);
      float4 vb = *reinterpret_cast<const float4*>(tb + cc);
      a = fmaf(va.x, WA[cc + 0][o], a);
      a = fmaf(va.y, WA[cc + 1][o], a);
      a = fmaf(va.z, WA[cc + 2][o], a);
      a = fmaf(va.w, WA[cc + 3][o], a);
      a = fmaf(vb.x, WB[cc + 0][o], a);
      a = fmaf(vb.y, WB[cc + 1][o], a);
      a = fmaf(vb.z, WB[cc + 2][o], a);
      a = fmaf(vb.w, WB[cc + 3][o], a);
    }
    int oi = r * 64 + o;
    float res = a + (accumulate ? out[oi] : 0.f);
    if (finalize) res = fmaxf(res + bias_s[o], 0.f);
    out[oi] = res;
  }
}

extern "C" void kernel_launch(void* const* d_in, const int* in_sizes, int n_in,
                              void* d_out, int out_size, void* d_ws, size_t ws_size,
                              hipStream_t stream) {
  const float* x        = (const float*)d_in[0];
  const int*   lap_rows = (const int*)d_in[1];
  const int*   lap_cols = (const int*)d_in[2];
  const float* lap_vals = (const float*)d_in[3];
  const float* weights  = (const float*)d_in[4];  // [4][64][64]
  const float* bias     = (const float*)d_in[5];
  float* out = (float*)d_out;

  // Workspace carve-out (~110 MB total)
  char* ws = (char*)d_ws;
  size_t off = 0;
  auto alloc = [&](size_t bytes) {
    void* p = ws + off;
    off += (bytes + 255) & ~(size_t)255;
    return p;
  };
  int*   counts    = (int*)alloc((size_t)N_NODES * 4);
  int*   row_start = (int*)alloc((size_t)(N_NODES + 1) * 4);
  int*   cursor    = (int*)alloc((size_t)N_NODES * 4);
  int*   cols_s    = (int*)alloc((size_t)N_EDGES * 4);
  float* vals_s    = (float*)alloc((size_t)N_EDGES * 4);
  float* bufA      = (float*)alloc((size_t)BATCH * BN * 4);
  float* bufB      = (float*)alloc((size_t)BATCH * BN * 4);
  (void)ws_size; (void)in_sizes; (void)n_in; (void)out_size;

  // --- Build CSR (by destination row) ---
  hipMemsetAsync(counts, 0, (size_t)N_NODES * 4, stream);
  hist_kernel<<<(N_EDGES + 255) / 256, 256, 0, stream>>>(lap_rows, counts);
  scan_kernel<<<1, 1024, 0, stream>>>(counts, row_start, cursor);
  fill_kernel<<<(N_EDGES + 255) / 256, 256, 0, stream>>>(lap_rows, lap_cols, lap_vals,
                                                         cursor, cols_s, vals_s);

  const int spmm_blocks = (N_NODES * 16 + 255) / 256;  // 3125
  const int gemm_blocks = ROWS_TOTAL / 64;             // 3125

  // T1 = L x
  spmm_csr<<<spmm_blocks, 256, 0, stream>>>(row_start, cols_s, vals_s, x, nullptr, bufA, 1.0f);
  // out = x@W0 + T1@W1
  gemm2_kernel<<<gemm_blocks, 256, 0, stream>>>(x, bufA, weights, weights + 4096,
                                                nullptr, out, 0, 0);
  // T2 = 2 L T1 - x
  spmm_csr<<<spmm_blocks, 256, 0, stream>>>(row_start, cols_s, vals_s, bufA, x, bufB, 2.0f);
  // T3 = 2 L T2 - T1   (dst aliases sub: safe, 1:1 thread<->element, read-then-write)
  spmm_csr<<<spmm_blocks, 256, 0, stream>>>(row_start, cols_s, vals_s, bufB, bufA, bufA, 2.0f);
  // out = relu(out + T2@W2 + T3@W3 + bias)
  gemm2_kernel<<<gemm_blocks, 256, 0, stream>>>(bufB, bufA, weights + 2 * 4096, weights + 3 * 4096,
                                                bias, out, 1, 1);
}

// Round 2
// 699.185 us; speedup vs baseline: 1.6644x; 1.6644x over previous
//
#include <hip/hip_runtime.h>

// ChebyshevGCNN: out = relu(bias + x@W0 + T1@W1 + T2@W2 + T3@W3)
// Reassociated: S1=Lx, S2=LS1, S3=LS2;  T2=2S2-x, T3=4S3-3S1
//   => out = relu(bias + x@(W0-W2) + S1@(W1-3W3) + S2@(2W2) + S3@(4W3))
// So SpMM passes are pure dst = L*src (no subtract traffic), and the four
// modified weight matrices are precomputed by a tiny transform kernel.

#define N_NODES 50000
#define N_EDGES 800000
#define BATCH 4
#define CH 64
#define BN (N_NODES * CH)             // elems per batch matrix = 3,200,000
#define ROWS_TOTAL (BATCH * N_NODES)  // 200,000

__global__ void hist_kernel(const int* __restrict__ rows, int* __restrict__ counts) {
  int e = blockIdx.x * blockDim.x + threadIdx.x;
  if (e < N_EDGES) atomicAdd(&counts[rows[e]], 1);
}

// Single-block exclusive scan over N_NODES counts -> row_start[N+1], cursor[N]
__global__ void scan_kernel(const int* __restrict__ counts,
                            int* __restrict__ row_start,
                            int* __restrict__ cursor) {
  __shared__ int sums[1024];
  int tid = threadIdx.x;
  const int per = (N_NODES + 1023) / 1024;  // 49
  int begin = tid * per;
  int end = begin + per; if (end > N_NODES) end = N_NODES;
  int s = 0;
  for (int i = begin; i < end; ++i) s += counts[i];
  sums[tid] = s;
  __syncthreads();
  for (int off = 1; off < 1024; off <<= 1) {
    int t = (tid >= off) ? sums[tid - off] : 0;
    __syncthreads();
    sums[tid] += t;
    __syncthreads();
  }
  int running = sums[tid] - s;  // exclusive prefix
  for (int i = begin; i < end; ++i) {
    row_start[i] = running;
    cursor[i] = running;
    running += counts[i];
  }
  if (tid == 0) row_start[N_NODES] = N_EDGES;
}

__global__ void fill_kernel(const int* __restrict__ rows, const int* __restrict__ cols,
                            const float* __restrict__ vals, int* cursor,
                            int* __restrict__ cols_s, float* __restrict__ vals_s) {
  int e = blockIdx.x * blockDim.x + threadIdx.x;
  if (e >= N_EDGES) return;
  int r = rows[e];
  int pos = atomicAdd(&cursor[r], 1);
  cols_s[pos] = cols[e];
  vals_s[pos] = vals[e];
}

// Precompute modified weights: Wt0=W0-W2, Wt1=W1-3W3, Wt2=2W2, Wt3=4W3
__global__ __launch_bounds__(256) void wtransform_kernel(const float* __restrict__ w,
                                                         float* __restrict__ wt) {
  int i = blockIdx.x * 256 + threadIdx.x;
  if (i >= 4096) return;
  float w0 = w[i], w1 = w[4096 + i], w2 = w[8192 + i], w3 = w[12288 + i];
  wt[i]          = w0 - w2;
  wt[4096 + i]   = w1 - 3.0f * w3;
  wt[8192 + i]   = 2.0f * w2;
  wt[12288 + i]  = 4.0f * w3;
}

// dst = L * src (all 4 batches). One wave per row: lane = (batch, chan-group).
// Per edge: one coalesced 1KB gather instruction (4 batches x 256B) + 4 FMAs/lane.
__global__ __launch_bounds__(256) void spmm_kernel(const int* __restrict__ row_start,
                                                   const int* __restrict__ cols_s,
                                                   const float* __restrict__ vals_s,
                                                   const float* __restrict__ src,
                                                   float* __restrict__ dst) {
  int row = blockIdx.x * 4 + (threadIdx.x >> 6);   // grid covers exactly N_NODES
  int lane = threadIdx.x & 63;
  int b = lane >> 4;            // batch 0..3
  int c = (lane & 15) << 2;     // channel offset 0,4,...,60
  const float* srcb = src + (size_t)b * BN + c;
  int s = row_start[row], e = row_start[row + 1];
  float ax = 0.f, ay = 0.f, az = 0.f, aw = 0.f;
  for (int i = s; i < e; ++i) {
    int col = cols_s[i];
    float v = vals_s[i];
    float4 sv = *reinterpret_cast<const float4*>(srcb + (size_t)col * CH);
    ax = fmaf(v, sv.x, ax);
    ay = fmaf(v, sv.y, ay);
    az = fmaf(v, sv.z, az);
    aw = fmaf(v, sv.w, aw);
  }
  float4 r = make_float4(ax, ay, az, aw);
  *reinterpret_cast<float4*>(dst + (size_t)b * BN + (size_t)row * CH + c) = r;
}

__device__ inline void fma_row(const float4 a, const float4* w, float4& acc) {
  acc.x = fmaf(a.x, w[0].x, acc.x);
  acc.y = fmaf(a.x, w[0].y, acc.y);
  acc.z = fmaf(a.x, w[0].z, acc.z);
  acc.w = fmaf(a.x, w[0].w, acc.w);
  acc.x = fmaf(a.y, w[1].x, acc.x);
  acc.y = fmaf(a.y, w[1].y, acc.y);
  acc.z = fmaf(a.y, w[1].z, acc.z);
  acc.w = fmaf(a.y, w[1].w, acc.w);
  acc.x = fmaf(a.z, w[2].x, acc.x);
  acc.y = fmaf(a.z, w[2].y, acc.y);
  acc.z = fmaf(a.z, w[2].z, acc.z);
  acc.w = fmaf(a.z, w[2].w, acc.w);
  acc.x = fmaf(a.w, w[3].x, acc.x);
  acc.y = fmaf(a.w, w[3].y, acc.y);
  acc.z = fmaf(a.w, w[3].z, acc.z);
  acc.w = fmaf(a.w, w[3].w, acc.w);
}

// out[r][o] (+)= Ta[r][:]@Wa[:,o] + Tb[r][:]@Wb[:,o]  (+bias, relu if finalize)
// Thread = 4 rows x 4 out-channels: 4 independent float4 acc chains.
// Weights staged in LDS [k][o]; ds_read_b128 is 2-way-per-bank = conflict-free.
__global__ __launch_bounds__(256) void gemm2_kernel(
    const float* __restrict__ Ta, const float* __restrict__ Tb,
    const float* __restrict__ Wa, const float* __restrict__ Wb,
    const float* __restrict__ bias, float* out,
    int accumulate, int finalize) {
  __shared__ float WA[64][64];
  __shared__ float WB[64][64];
  __shared__ float bias_s[64];
  for (int i = threadIdx.x; i < 4096; i += 256) {
    WA[i >> 6][i & 63] = Wa[i];
    WB[i >> 6][i & 63] = Wb[i];
  }
  if (threadIdx.x < 64) bias_s[threadIdx.x] = bias ? bias[threadIdx.x] : 0.f;
  __syncthreads();

  const int og = threadIdx.x & 15;   // out-channel group
  const int rg = threadIdx.x >> 4;   // row group 0..15
  const int o4 = og << 2;
  const size_t r0 = (size_t)blockIdx.x * 64 + (size_t)rg * 4;
  const float* ta = Ta + r0 * CH;
  const float* tb = Tb + r0 * CH;

  float4 acc[4];
#pragma unroll
  for (int r = 0; r < 4; ++r) acc[r] = make_float4(0.f, 0.f, 0.f, 0.f);

#pragma unroll 4
  for (int cc = 0; cc < 64; cc += 4) {
    float4 wa[4], wb[4];
#pragma unroll
    for (int k = 0; k < 4; ++k) {
      wa[k] = *reinterpret_cast<const float4*>(&WA[cc + k][o4]);
      wb[k] = *reinterpret_cast<const float4*>(&WB[cc + k][o4]);
    }
#pragma unroll
    for (int r = 0; r < 4; ++r) {
      float4 a = *reinterpret_cast<const float4*>(ta + r * CH + cc);
      float4 b = *reinterpret_cast<const float4*>(tb + r * CH + cc);
      fma_row(a, wa, acc[r]);
      fma_row(b, wb, acc[r]);
    }
  }

#pragma unroll
  for (int r = 0; r < 4; ++r) {
    size_t oi = (r0 + r) * CH + o4;
    float4 res = acc[r];
    if (accumulate) {
      float4 p = *reinterpret_cast<const float4*>(out + oi);
      res.x += p.x; res.y += p.y; res.z += p.z; res.w += p.w;
    }
    if (finalize) {
      res.x = fmaxf(res.x + bias_s[o4 + 0], 0.f);
      res.y = fmaxf(res.y + bias_s[o4 + 1], 0.f);
      res.z = fmaxf(res.z + bias_s[o4 + 2], 0.f);
      res.w = fmaxf(res.w + bias_s[o4 + 3], 0.f);
    }
    *reinterpret_cast<float4*>(out + oi) = res;
  }
}

extern "C" void kernel_launch(void* const* d_in, const int* in_sizes, int n_in,
                              void* d_out, int out_size, void* d_ws, size_t ws_size,
                              hipStream_t stream) {
  const float* x        = (const float*)d_in[0];
  const int*   lap_rows = (const int*)d_in[1];
  const int*   lap_cols = (const int*)d_in[2];
  const float* lap_vals = (const float*)d_in[3];
  const float* weights  = (const float*)d_in[4];  // [4][64][64]
  const float* bias     = (const float*)d_in[5];
  float* out = (float*)d_out;

  char* ws = (char*)d_ws;
  size_t off = 0;
  auto alloc = [&](size_t bytes) {
    void* p = ws + off;
    off += (bytes + 255) & ~(size_t)255;
    return p;
  };
  int*   counts    = (int*)alloc((size_t)N_NODES * 4);
  int*   row_start = (int*)alloc((size_t)(N_NODES + 1) * 4);
  int*   cursor    = (int*)alloc((size_t)N_NODES * 4);
  int*   cols_s    = (int*)alloc((size_t)N_EDGES * 4);
  float* vals_s    = (float*)alloc((size_t)N_EDGES * 4);
  float* wt        = (float*)alloc((size_t)4 * 64 * 64 * 4);
  float* bufA      = (float*)alloc((size_t)BATCH * BN * 4);
  float* bufB      = (float*)alloc((size_t)BATCH * BN * 4);
  (void)ws_size; (void)in_sizes; (void)n_in; (void)out_size;

  // --- Weight transform + CSR build ---
  wtransform_kernel<<<16, 256, 0, stream>>>(weights, wt);
  hipMemsetAsync(counts, 0, (size_t)N_NODES * 4, stream);
  hist_kernel<<<(N_EDGES + 255) / 256, 256, 0, stream>>>(lap_rows, counts);
  scan_kernel<<<1, 1024, 0, stream>>>(counts, row_start, cursor);
  fill_kernel<<<(N_EDGES + 255) / 256, 256, 0, stream>>>(lap_rows, lap_cols, lap_vals,
                                                         cursor, cols_s, vals_s);

  const int spmm_blocks = N_NODES / 4;     // 12500, one wave per row
  const int gemm_blocks = ROWS_TOTAL / 64; // 3125

  // S1 = L x
  spmm_kernel<<<spmm_blocks, 256, 0, stream>>>(row_start, cols_s, vals_s, x, bufA);
  // out = x@Wt0 + S1@Wt1
  gemm2_kernel<<<gemm_blocks, 256, 0, stream>>>(x, bufA, wt, wt + 4096,
                                                nullptr, out, 0, 0);
  // S2 = L S1
  spmm_kernel<<<spmm_blocks, 256, 0, stream>>>(row_start, cols_s, vals_s, bufA, bufB);
  // S3 = L S2 (overwrites S1; S1 no longer needed)
  spmm_kernel<<<spmm_blocks, 256, 0, stream>>>(row_start, cols_s, vals_s, bufB, bufA);
  // out = relu(out + S2@Wt2 + S3@Wt3 + bias)
  gemm2_kernel<<<gemm_blocks, 256, 0, stream>>>(bufB, bufA, wt + 8192, wt + 12288,
                                                bias, out, 1, 1);
}

// Round 3
// 550.980 us; speedup vs baseline: 2.1121x; 1.2690x over previous
//
#include <hip/hip_runtime.h>

// ChebyshevGCNN: out = relu(bias + x@W0 + T1@W1 + T2@W2 + T3@W3)
// Reassociated: S1=Lx, S2=LS1, S3=LS2;  T2=2S2-x, T3=4S3-3S1
//   => out = relu(bias + x@(W0-W2) + S1@(W1-3W3) + S2@(2W2) + S3@(4W3))
// This round: all SpMM operands stored as bf16 (halves gather traffic, makes
// the 25.6MB src footprint cache-resident), 2-edge-per-wave 16B gathers,
// and a single fused 4-matrix dense pass (no out re-read).

#define N_NODES 50000
#define N_EDGES 800000
#define BATCH 4
#define CH 64
#define BN (N_NODES * CH)             // elems per batch matrix
#define BNW (BN / 2)                  // u32 words per batch matrix (bf16x2)
#define ROWS_TOTAL (BATCH * N_NODES)  // 200,000

typedef unsigned int uint;

__device__ __forceinline__ float bf16lo(uint u) { return __uint_as_float(u << 16); }
__device__ __forceinline__ float bf16hi(uint u) { return __uint_as_float(u & 0xffff0000u); }
__device__ __forceinline__ uint pack_bf16(float lo, float hi) {
  uint a = __float_as_uint(lo);
  uint b = __float_as_uint(hi);
  a = (a + 0x7fffu + ((a >> 16) & 1u)) >> 16;  // RN-even
  b = (b + 0x7fffu + ((b >> 16) & 1u)) >> 16;
  return a | (b << 16);
}

// ---------------- CSR build ----------------
__global__ void hist_kernel(const int* __restrict__ rows, int* __restrict__ counts) {
  int e = blockIdx.x * blockDim.x + threadIdx.x;
  if (e < N_EDGES) atomicAdd(&counts[rows[e]], 1);
}

__global__ void scan_kernel(const int* __restrict__ counts,
                            int* __restrict__ row_start,
                            int* __restrict__ cursor) {
  __shared__ int sums[1024];
  int tid = threadIdx.x;
  const int per = (N_NODES + 1023) / 1024;  // 49
  int begin = tid * per;
  int end = begin + per; if (end > N_NODES) end = N_NODES;
  int s = 0;
  for (int i = begin; i < end; ++i) s += counts[i];
  sums[tid] = s;
  __syncthreads();
  for (int off = 1; off < 1024; off <<= 1) {
    int t = (tid >= off) ? sums[tid - off] : 0;
    __syncthreads();
    sums[tid] += t;
    __syncthreads();
  }
  int running = sums[tid] - s;
  for (int i = begin; i < end; ++i) {
    row_start[i] = running;
    cursor[i] = running;
    running += counts[i];
  }
  if (tid == 0) row_start[N_NODES] = N_EDGES;
}

__global__ void fill_kernel(const int* __restrict__ rows, const int* __restrict__ cols,
                            const float* __restrict__ vals, int* cursor,
                            int* __restrict__ cols_s, float* __restrict__ vals_s) {
  int e = blockIdx.x * blockDim.x + threadIdx.x;
  if (e >= N_EDGES) return;
  int r = rows[e];
  int pos = atomicAdd(&cursor[r], 1);
  cols_s[pos] = cols[e];
  vals_s[pos] = vals[e];
}

// Wt0=W0-W2, Wt1=W1-3W3, Wt2=2W2, Wt3=4W3  (kept f32 for LDS staging)
__global__ __launch_bounds__(256) void wtransform_kernel(const float* __restrict__ w,
                                                         float* __restrict__ wt) {
  int i = blockIdx.x * 256 + threadIdx.x;
  if (i >= 4096) return;
  float w0 = w[i], w1 = w[4096 + i], w2 = w[8192 + i], w3 = w[12288 + i];
  wt[i]         = w0 - w2;
  wt[4096 + i]  = w1 - 3.0f * w3;
  wt[8192 + i]  = 2.0f * w2;
  wt[12288 + i] = 4.0f * w3;
}

// f32 -> packed bf16 (8 elems/thread)
__global__ __launch_bounds__(256) void cvt_bf16_kernel(const float* __restrict__ in,
                                                       uint* __restrict__ outw) {
  int i = blockIdx.x * 256 + threadIdx.x;
  if (i >= (BATCH * BN) / 8) return;
  float4 a = reinterpret_cast<const float4*>(in)[i * 2];
  float4 b = reinterpret_cast<const float4*>(in)[i * 2 + 1];
  uint4 r;
  r.x = pack_bf16(a.x, a.y);
  r.y = pack_bf16(a.z, a.w);
  r.z = pack_bf16(b.x, b.y);
  r.w = pack_bf16(b.z, b.w);
  reinterpret_cast<uint4*>(outw)[i] = r;
}

// dst = L * src, bf16 in / bf16 out, all 4 batches.
// One wave per row; lanes 0-31 process even edges, 32-63 odd edges (2 edges in
// flight, 16B gathers), fold via shfl_xor(32) at the end.
__global__ __launch_bounds__(256) void spmm_bf16(const int* __restrict__ row_start,
                                                 const int* __restrict__ cols_s,
                                                 const float* __restrict__ vals_s,
                                                 const uint* __restrict__ src,
                                                 uint* __restrict__ dst) {
  int row = blockIdx.x * 4 + (threadIdx.x >> 6);
  int lane = threadIdx.x & 63;
  int half = lane >> 5;
  int b = (lane >> 3) & 3;        // batch
  int cw = (lane & 7) * 4;        // u32-word offset in row (8 bf16 = 4 words)
  const uint* srcb = src + (size_t)b * BNW + cw;
  int s = row_start[row], e = row_start[row + 1];
  float acc[8];
#pragma unroll
  for (int j = 0; j < 8; ++j) acc[j] = 0.f;
  for (int i = s + half; i < e; i += 2) {
    int col = cols_s[i];
    float v = vals_s[i];
    uint4 w = *reinterpret_cast<const uint4*>(srcb + (size_t)col * (CH / 2));
    acc[0] = fmaf(v, bf16lo(w.x), acc[0]);
    acc[1] = fmaf(v, bf16hi(w.x), acc[1]);
    acc[2] = fmaf(v, bf16lo(w.y), acc[2]);
    acc[3] = fmaf(v, bf16hi(w.y), acc[3]);
    acc[4] = fmaf(v, bf16lo(w.z), acc[4]);
    acc[5] = fmaf(v, bf16hi(w.z), acc[5]);
    acc[6] = fmaf(v, bf16lo(w.w), acc[6]);
    acc[7] = fmaf(v, bf16hi(w.w), acc[7]);
  }
#pragma unroll
  for (int j = 0; j < 8; ++j) acc[j] += __shfl_xor(acc[j], 32, 64);
  if (half == 0) {
    uint4 r;
    r.x = pack_bf16(acc[0], acc[1]);
    r.y = pack_bf16(acc[2], acc[3]);
    r.z = pack_bf16(acc[4], acc[5]);
    r.w = pack_bf16(acc[6], acc[7]);
    *reinterpret_cast<uint4*>(dst + (size_t)b * BNW + (size_t)row * (CH / 2) + cw) = r;
  }
}

__device__ __forceinline__ void fma4(float4& acc, float a, const float4 w) {
  acc.x = fmaf(a, w.x, acc.x);
  acc.y = fmaf(a, w.y, acc.y);
  acc.z = fmaf(a, w.z, acc.z);
  acc.w = fmaf(a, w.w, acc.w);
}

// out = relu(bias + A0@Wt0 + A1@Wt1 + A2@Wt2 + A3@Wt3), A* bf16-packed, out f32.
// Thread = 4 rows x 4 out-channels. All 4 weight matrices in LDS (64KB).
__global__ __launch_bounds__(256) void gemm4_kernel(
    const uint* __restrict__ A0, const uint* __restrict__ A1,
    const uint* __restrict__ A2, const uint* __restrict__ A3,
    const float* __restrict__ wt, const float* __restrict__ bias,
    float* __restrict__ out) {
  __shared__ float WS[4][64][64];
  __shared__ float bias_s[64];
  for (int i = threadIdx.x; i < 4 * 4096; i += 256)
    WS[i >> 12][(i >> 6) & 63][i & 63] = wt[i];
  if (threadIdx.x < 64) bias_s[threadIdx.x] = bias[threadIdx.x];
  __syncthreads();

  const int o4 = (threadIdx.x & 15) << 2;
  const int rg = threadIdx.x >> 4;
  const size_t r0 = (size_t)blockIdx.x * 64 + (size_t)rg * 4;
  const uint* As[4] = {A0 + r0 * 32, A1 + r0 * 32, A2 + r0 * 32, A3 + r0 * 32};

  float4 acc[4];
#pragma unroll
  for (int r = 0; r < 4; ++r) acc[r] = make_float4(0.f, 0.f, 0.f, 0.f);

#pragma unroll 2
  for (int cc = 0; cc < 64; cc += 4) {
    float4 w[4][4];
#pragma unroll
    for (int m = 0; m < 4; ++m)
#pragma unroll
      for (int kk = 0; kk < 4; ++kk)
        w[m][kk] = *reinterpret_cast<const float4*>(&WS[m][cc + kk][o4]);
#pragma unroll
    for (int r = 0; r < 4; ++r) {
#pragma unroll
      for (int m = 0; m < 4; ++m) {
        uint2 av = *reinterpret_cast<const uint2*>(As[m] + r * 32 + (cc >> 1));
        fma4(acc[r], bf16lo(av.x), w[m][0]);
        fma4(acc[r], bf16hi(av.x), w[m][1]);
        fma4(acc[r], bf16lo(av.y), w[m][2]);
        fma4(acc[r], bf16hi(av.y), w[m][3]);
      }
    }
  }

#pragma unroll
  for (int r = 0; r < 4; ++r) {
    size_t oi = (r0 + r) * CH + o4;
    float4 res = acc[r];
    res.x = fmaxf(res.x + bias_s[o4 + 0], 0.f);
    res.y = fmaxf(res.y + bias_s[o4 + 1], 0.f);
    res.z = fmaxf(res.z + bias_s[o4 + 2], 0.f);
    res.w = fmaxf(res.w + bias_s[o4 + 3], 0.f);
    *reinterpret_cast<float4*>(out + oi) = res;
  }
}

extern "C" void kernel_launch(void* const* d_in, const int* in_sizes, int n_in,
                              void* d_out, int out_size, void* d_ws, size_t ws_size,
                              hipStream_t stream) {
  const float* x        = (const float*)d_in[0];
  const int*   lap_rows = (const int*)d_in[1];
  const int*   lap_cols = (const int*)d_in[2];
  const float* lap_vals = (const float*)d_in[3];
  const float* weights  = (const float*)d_in[4];  // [4][64][64]
  const float* bias     = (const float*)d_in[5];
  float* out = (float*)d_out;

  char* ws = (char*)d_ws;
  size_t off = 0;
  auto alloc = [&](size_t bytes) {
    void* p = ws + off;
    off += (bytes + 255) & ~(size_t)255;
    return p;
  };
  int*   counts    = (int*)alloc((size_t)N_NODES * 4);
  int*   row_start = (int*)alloc((size_t)(N_NODES + 1) * 4);
  int*   cursor    = (int*)alloc((size_t)N_NODES * 4);
  int*   cols_s    = (int*)alloc((size_t)N_EDGES * 4);
  float* vals_s    = (float*)alloc((size_t)N_EDGES * 4);
  float* wt        = (float*)alloc((size_t)4 * 4096 * 4);
  uint*  xb        = (uint*)alloc((size_t)BATCH * BNW * 4);   // bf16 x
  uint*  S1        = (uint*)alloc((size_t)BATCH * BNW * 4);
  uint*  S2        = (uint*)alloc((size_t)BATCH * BNW * 4);
  uint*  S3        = (uint*)alloc((size_t)BATCH * BNW * 4);
  (void)ws_size; (void)in_sizes; (void)n_in; (void)out_size;

  // Weight transform + x->bf16 + CSR build
  wtransform_kernel<<<16, 256, 0, stream>>>(weights, wt);
  cvt_bf16_kernel<<<(BATCH * BN / 8 + 255) / 256, 256, 0, stream>>>(x, xb);
  hipMemsetAsync(counts, 0, (size_t)N_NODES * 4, stream);
  hist_kernel<<<(N_EDGES + 255) / 256, 256, 0, stream>>>(lap_rows, counts);
  scan_kernel<<<1, 1024, 0, stream>>>(counts, row_start, cursor);
  fill_kernel<<<(N_EDGES + 255) / 256, 256, 0, stream>>>(lap_rows, lap_cols, lap_vals,
                                                         cursor, cols_s, vals_s);

  const int spmm_blocks = N_NODES / 4;  // 12500, one wave per row

  // S1 = L x ; S2 = L S1 ; S3 = L S2
  spmm_bf16<<<spmm_blocks, 256, 0, stream>>>(row_start, cols_s, vals_s, xb, S1);
  spmm_bf16<<<spmm_blocks, 256, 0, stream>>>(row_start, cols_s, vals_s, S1, S2);
  spmm_bf16<<<spmm_blocks, 256, 0, stream>>>(row_start, cols_s, vals_s, S2, S3);
  // out = relu(bias + x@Wt0 + S1@Wt1 + S2@Wt2 + S3@Wt3)
  gemm4_kernel<<<ROWS_TOTAL / 64, 256, 0, stream>>>(xb, S1, S2, S3, wt, bias, out);
}

// Round 4
// 408.339 us; speedup vs baseline: 2.8499x; 1.3493x over previous
//
#include <hip/hip_runtime.h>

// ChebyshevGCNN: out = relu(bias + x@W0 + T1@W1 + T2@W2 + T3@W3)
// Reassociated: S1=Lx, S2=LS1, S3=LS2;  T2=2S2-x, T3=4S3-3S1
//   => out = relu(bias + x@(W0-W2) + S1@(W1-3W3) + S2@(2W2) + S3@(4W3))
// Round 4: dense pass on MFMA (bf16, K=256 fused), SpMM operands in
// node-interleaved layout [node][batch][ch] so each edge gather is one
// contiguous 512B block; 2-deep edge unroll; (col,val) packed uint2.

#define N_NODES 50000
#define N_EDGES 800000
#define BATCH 4
#define CH 64
#define BN (N_NODES * CH)             // elems per batch matrix (out layout)
#define ROWS_TOTAL (BATCH * N_NODES)  // 200,000

typedef unsigned int uint;
typedef unsigned short ushort;
typedef __attribute__((ext_vector_type(8))) short short8;   // 8 x bf16
typedef __attribute__((ext_vector_type(4))) float f32x4;

__device__ __forceinline__ float bf16lo(uint u) { return __uint_as_float(u << 16); }
__device__ __forceinline__ float bf16hi(uint u) { return __uint_as_float(u & 0xffff0000u); }
__device__ __forceinline__ uint pack_bf16(float lo, float hi) {
  uint a = __float_as_uint(lo);
  uint b = __float_as_uint(hi);
  a = (a + 0x7fffu + ((a >> 16) & 1u)) >> 16;  // RN-even
  b = (b + 0x7fffu + ((b >> 16) & 1u)) >> 16;
  return a | (b << 16);
}
__device__ __forceinline__ ushort bf16one(float x) {
  uint a = __float_as_uint(x);
  a = (a + 0x7fffu + ((a >> 16) & 1u)) >> 16;
  return (ushort)a;
}

// ---------------- CSR build ----------------
__global__ void hist_kernel(const int* __restrict__ rows, int* __restrict__ counts) {
  int e = blockIdx.x * blockDim.x + threadIdx.x;
  if (e < N_EDGES) atomicAdd(&counts[rows[e]], 1);
}

__global__ void scan_kernel(const int* __restrict__ counts,
                            int* __restrict__ row_start,
                            int* __restrict__ cursor) {
  __shared__ int sums[1024];
  int tid = threadIdx.x;
  const int per = (N_NODES + 1023) / 1024;  // 49
  int begin = tid * per;
  int end = begin + per; if (end > N_NODES) end = N_NODES;
  int s = 0;
  for (int i = begin; i < end; ++i) s += counts[i];
  sums[tid] = s;
  __syncthreads();
  for (int off = 1; off < 1024; off <<= 1) {
    int t = (tid >= off) ? sums[tid - off] : 0;
    __syncthreads();
    sums[tid] += t;
    __syncthreads();
  }
  int running = sums[tid] - s;
  for (int i = begin; i < end; ++i) {
    row_start[i] = running;
    cursor[i] = running;
    running += counts[i];
  }
  if (tid == 0) row_start[N_NODES] = N_EDGES;
}

__global__ void fill_kernel(const int* __restrict__ rows, const int* __restrict__ cols,
                            const float* __restrict__ vals, int* cursor,
                            uint2* __restrict__ pairs) {
  int e = blockIdx.x * blockDim.x + threadIdx.x;
  if (e >= N_EDGES) return;
  int r = rows[e];
  int pos = atomicAdd(&cursor[r], 1);
  pairs[pos] = make_uint2((uint)cols[e], __float_as_uint(vals[e]));
}

// Modified weights, transposed + bf16: wtT[o][k], k = m*64+c, m in 0..3.
// Wt0=W0-W2, Wt1=W1-3W3, Wt2=2W2, Wt3=4W3.  w layout: [m][c][o].
__global__ __launch_bounds__(256) void wprep_kernel(const float* __restrict__ w,
                                                    ushort* __restrict__ wtT) {
  int t = blockIdx.x * 256 + threadIdx.x;
  if (t >= 64 * 256) return;
  int o = t >> 8, k = t & 255, m = k >> 6, c = k & 63;
  int idx = c * 64 + o;
  float v;
  if (m == 0)      v = w[idx] - w[2 * 4096 + idx];
  else if (m == 1) v = w[4096 + idx] - 3.0f * w[3 * 4096 + idx];
  else if (m == 2) v = 2.0f * w[2 * 4096 + idx];
  else             v = 4.0f * w[3 * 4096 + idx];
  wtT[t] = bf16one(v);
}

// f32 [b][node][64] -> bf16 interleaved [node][b][64] (word layout [node][128w])
__global__ __launch_bounds__(256) void cvt_interleave_kernel(const float* __restrict__ in,
                                                             uint* __restrict__ outw) {
  int t = blockIdx.x * 256 + threadIdx.x;  // 1.6M threads, 8 elems each
  if (t >= (BATCH * BN) / 8) return;
  int c8 = t & 7;
  int b = (t >> 3) & 3;
  int node = t >> 5;
  const float* p = in + (size_t)b * BN + (size_t)node * 64 + c8 * 8;
  float4 a = *reinterpret_cast<const float4*>(p);
  float4 bb = *reinterpret_cast<const float4*>(p + 4);
  uint4 r;
  r.x = pack_bf16(a.x, a.y);
  r.y = pack_bf16(a.z, a.w);
  r.z = pack_bf16(bb.x, bb.y);
  r.w = pack_bf16(bb.z, bb.w);
  *reinterpret_cast<uint4*>(outw + (size_t)node * 128 + b * 32 + c8 * 4) = r;
}

// dst = L * src, bf16 interleaved [node][b][ch]. One wave per dest row.
// Per edge: one contiguous 512B gather (32 lanes x 16B); lanes 0-31 = even
// edges, 32-63 = odd edges; 2-deep unroll per half; shfl fold at end.
__global__ __launch_bounds__(256) void spmm_bf16(const int* __restrict__ row_start,
                                                 const uint2* __restrict__ pairs,
                                                 const uint* __restrict__ src,
                                                 uint* __restrict__ dst) {
  int row = blockIdx.x * 4 + (threadIdx.x >> 6);
  int lane = threadIdx.x & 63;
  int half = lane >> 5;
  int hl = lane & 31;
  const uint* srcw = src + hl * 4;
  int s = row_start[row], e = row_start[row + 1];
  float acc[8];
#pragma unroll
  for (int j = 0; j < 8; ++j) acc[j] = 0.f;
  int i = s + half;
  for (; i + 2 < e; i += 4) {
    uint2 p0 = pairs[i];
    uint2 p1 = pairs[i + 2];
    uint4 w0 = *reinterpret_cast<const uint4*>(srcw + (size_t)p0.x * 128);
    uint4 w1 = *reinterpret_cast<const uint4*>(srcw + (size_t)p1.x * 128);
    float v0 = __uint_as_float(p0.y);
    float v1 = __uint_as_float(p1.y);
    acc[0] = fmaf(v0, bf16lo(w0.x), acc[0]);
    acc[1] = fmaf(v0, bf16hi(w0.x), acc[1]);
    acc[2] = fmaf(v0, bf16lo(w0.y), acc[2]);
    acc[3] = fmaf(v0, bf16hi(w0.y), acc[3]);
    acc[4] = fmaf(v0, bf16lo(w0.z), acc[4]);
    acc[5] = fmaf(v0, bf16hi(w0.z), acc[5]);
    acc[6] = fmaf(v0, bf16lo(w0.w), acc[6]);
    acc[7] = fmaf(v0, bf16hi(w0.w), acc[7]);
    acc[0] = fmaf(v1, bf16lo(w1.x), acc[0]);
    acc[1] = fmaf(v1, bf16hi(w1.x), acc[1]);
    acc[2] = fmaf(v1, bf16lo(w1.y), acc[2]);
    acc[3] = fmaf(v1, bf16hi(w1.y), acc[3]);
    acc[4] = fmaf(v1, bf16lo(w1.z), acc[4]);
    acc[5] = fmaf(v1, bf16hi(w1.z), acc[5]);
    acc[6] = fmaf(v1, bf16lo(w1.w), acc[6]);
    acc[7] = fmaf(v1, bf16hi(w1.w), acc[7]);
  }
  for (; i < e; i += 2) {
    uint2 p0 = pairs[i];
    uint4 w0 = *reinterpret_cast<const uint4*>(srcw + (size_t)p0.x * 128);
    float v0 = __uint_as_float(p0.y);
    acc[0] = fmaf(v0, bf16lo(w0.x), acc[0]);
    acc[1] = fmaf(v0, bf16hi(w0.x), acc[1]);
    acc[2] = fmaf(v0, bf16lo(w0.y), acc[2]);
    acc[3] = fmaf(v0, bf16hi(w0.y), acc[3]);
    acc[4] = fmaf(v0, bf16lo(w0.z), acc[4]);
    acc[5] = fmaf(v0, bf16hi(w0.z), acc[5]);
    acc[6] = fmaf(v0, bf16lo(w0.w), acc[6]);
    acc[7] = fmaf(v0, bf16hi(w0.w), acc[7]);
  }
#pragma unroll
  for (int j = 0; j < 8; ++j) acc[j] += __shfl_xor(acc[j], 32, 64);
  if (half == 0) {
    uint4 r;
    r.x = pack_bf16(acc[0], acc[1]);
    r.y = pack_bf16(acc[2], acc[3]);
    r.z = pack_bf16(acc[4], acc[5]);
    r.w = pack_bf16(acc[6], acc[7]);
    *reinterpret_cast<uint4*>(dst + (size_t)row * 128 + hl * 4) = r;
  }
}

// out = relu(bias + [x|S1|S2|S3] @ WtT^T), MFMA 16x16x32 bf16.
// Block = 4 waves; wave = 16 rows x 64 out-channels; K = 256 (8 steps).
// A read direct from global (interleaved rows, row stride 128B per matrix);
// B (weights) staged in LDS as [o][132 words] (pad kills stride-512B conflicts).
__global__ __launch_bounds__(256) void gemm4_mfma(
    const uint* __restrict__ A0, const uint* __restrict__ A1,
    const uint* __restrict__ A2, const uint* __restrict__ A3,
    const uint* __restrict__ wtT,   // [64][128] words (bf16 [64][256])
    const float* __restrict__ bias, float* __restrict__ out) {
  __shared__ uint WS[64 * 132];
  __shared__ float bias_s[64];
  for (int w = threadIdx.x; w < 8192; w += 256)
    WS[(w >> 7) * 132 + (w & 127)] = wtT[w];
  if (threadIdx.x < 64) bias_s[threadIdx.x] = bias[threadIdx.x];
  __syncthreads();

  const int lane = threadIdx.x & 63;
  const int wv = threadIdx.x >> 6;
  const int r0 = blockIdx.x * 64 + wv * 16;
  const int c16 = lane & 15;
  const int hi = lane >> 4;

  // per-lane A word offset: row = r0 + c16 (row stride 32 words), + hi*4
  const size_t arow = (size_t)(r0 + c16) * 32 + hi * 4;

  f32x4 acc[4] = {{0.f, 0.f, 0.f, 0.f}, {0.f, 0.f, 0.f, 0.f},
                  {0.f, 0.f, 0.f, 0.f}, {0.f, 0.f, 0.f, 0.f}};

#pragma unroll
  for (int ks = 0; ks < 8; ++ks) {
    const uint* ab = (ks >> 1) == 0 ? A0 : (ks >> 1) == 1 ? A1
                   : (ks >> 1) == 2 ? A2 : A3;
    uint4 av = *reinterpret_cast<const uint4*>(ab + arow + (ks & 1) * 16);
    short8 afrag = __builtin_bit_cast(short8, av);
#pragma unroll
    for (int nt = 0; nt < 4; ++nt) {
      uint4 bv = *reinterpret_cast<const uint4*>(
          &WS[(nt * 16 + c16) * 132 + ks * 16 + hi * 4]);
      short8 bfrag = __builtin_bit_cast(short8, bv);
      acc[nt] = __builtin_amdgcn_mfma_f32_16x16x32_bf16(afrag, bfrag, acc[nt], 0, 0, 0);
    }
  }

  // C/D layout: col = lane&15, row = (lane>>4)*4 + i  [verified m89/m91]
#pragma unroll
  for (int nt = 0; nt < 4; ++nt) {
#pragma unroll
    for (int i = 0; i < 4; ++i) {
      int row = r0 + hi * 4 + i;
      int node = row >> 2, b = row & 3;
      int col = nt * 16 + c16;
      float v = acc[nt][i] + bias_s[col];
      out[(size_t)b * BN + (size_t)node * 64 + col] = fmaxf(v, 0.f);
    }
  }
}

extern "C" void kernel_launch(void* const* d_in, const int* in_sizes, int n_in,
                              void* d_out, int out_size, void* d_ws, size_t ws_size,
                              hipStream_t stream) {
  const float* x        = (const float*)d_in[0];
  const int*   lap_rows = (const int*)d_in[1];
  const int*   lap_cols = (const int*)d_in[2];
  const float* lap_vals = (const float*)d_in[3];
  const float* weights  = (const float*)d_in[4];  // [4][64][64]
  const float* bias     = (const float*)d_in[5];
  float* out = (float*)d_out;

  char* ws = (char*)d_ws;
  size_t off = 0;
  auto alloc = [&](size_t bytes) {
    void* p = ws + off;
    off += (bytes + 255) & ~(size_t)255;
    return p;
  };
  int*    counts    = (int*)alloc((size_t)N_NODES * 4);
  int*    row_start = (int*)alloc((size_t)(N_NODES + 1) * 4);
  int*    cursor    = (int*)alloc((size_t)N_NODES * 4);
  uint2*  pairs     = (uint2*)alloc((size_t)N_EDGES * 8);
  ushort* wtT       = (ushort*)alloc((size_t)64 * 256 * 2);
  uint*   xb        = (uint*)alloc((size_t)ROWS_TOTAL * 32 * 4);  // 25.6MB each
  uint*   S1        = (uint*)alloc((size_t)ROWS_TOTAL * 32 * 4);
  uint*   S2        = (uint*)alloc((size_t)ROWS_TOTAL * 32 * 4);
  uint*   S3        = (uint*)alloc((size_t)ROWS_TOTAL * 32 * 4);
  (void)ws_size; (void)in_sizes; (void)n_in; (void)out_size;

  // Weight prep + x->bf16 interleave + CSR build
  wprep_kernel<<<64, 256, 0, stream>>>(weights, wtT);
  cvt_interleave_kernel<<<(BATCH * BN / 8 + 255) / 256, 256, 0, stream>>>(x, xb);
  hipMemsetAsync(counts, 0, (size_t)N_NODES * 4, stream);
  hist_kernel<<<(N_EDGES + 255) / 256, 256, 0, stream>>>(lap_rows, counts);
  scan_kernel<<<1, 1024, 0, stream>>>(counts, row_start, cursor);
  fill_kernel<<<(N_EDGES + 255) / 256, 256, 0, stream>>>(lap_rows, lap_cols, lap_vals,
                                                         cursor, pairs);

  const int spmm_blocks = N_NODES / 4;  // 12500, one wave per row

  // S1 = L x ; S2 = L S1 ; S3 = L S2
  spmm_bf16<<<spmm_blocks, 256, 0, stream>>>(row_start, pairs, xb, S1);
  spmm_bf16<<<spmm_blocks, 256, 0, stream>>>(row_start, pairs, S1, S2);
  spmm_bf16<<<spmm_blocks, 256, 0, stream>>>(row_start, pairs, S2, S3);
  // out = relu(bias + x@Wt0 + S1@Wt1 + S2@Wt2 + S3@Wt3)
  gemm4_mfma<<<ROWS_TOTAL / 64, 256, 0, stream>>>(xb, S1, S2, S3, (const uint*)wtT,
                                                  bias, out);
}

// Round 6
// 302.122 us; speedup vs baseline: 3.8518x; 1.3516x over previous
//
#include <hip/hip_runtime.h>

// ChebyshevGCNN: out = relu(bias + x@W0 + T1@W1 + T2@W2 + T3@W3)
// Reassociated: S1=Lx, S2=LS1, S3=LS2;  T2=2S2-x, T3=4S3-3S1
//   => out = relu(bias + x@(W0-W2) + S1@(W1-3W3) + S2@(2W2) + S3@(4W3))
// Round 6: fix macro-expansion bug (w.w) via inline fn; parallel 3-kernel scan;
// spmm gather unroll 4 edges in flight per half-wave.

#define N_NODES 50000
#define N_EDGES 800000
#define BATCH 4
#define CH 64
#define BN (N_NODES * CH)             // elems per batch matrix (out layout)
#define ROWS_TOTAL (BATCH * N_NODES)  // 200,000
#define SCAN_BLOCKS 196               // 196*256 = 50176 >= N_NODES

typedef unsigned int uint;
typedef unsigned short ushort;
typedef __attribute__((ext_vector_type(8))) short short8;   // 8 x bf16
typedef __attribute__((ext_vector_type(4))) float f32x4;

__device__ __forceinline__ float bf16lo(uint u) { return __uint_as_float(u << 16); }
__device__ __forceinline__ float bf16hi(uint u) { return __uint_as_float(u & 0xffff0000u); }
__device__ __forceinline__ uint pack_bf16(float lo, float hi) {
  uint a = __float_as_uint(lo);
  uint b = __float_as_uint(hi);
  a = (a + 0x7fffu + ((a >> 16) & 1u)) >> 16;  // RN-even
  b = (b + 0x7fffu + ((b >> 16) & 1u)) >> 16;
  return a | (b << 16);
}
__device__ __forceinline__ ushort bf16one(float x) {
  uint a = __float_as_uint(x);
  a = (a + 0x7fffu + ((a >> 16) & 1u)) >> 16;
  return (ushort)a;
}

// ---------------- CSR build ----------------
__global__ void hist_kernel(const int* __restrict__ rows, int* __restrict__ counts) {
  int e = blockIdx.x * blockDim.x + threadIdx.x;
  if (e < N_EDGES) atomicAdd(&counts[rows[e]], 1);
}

// 1/3: per-block (256-wide) sums of counts
__global__ __launch_bounds__(256) void partial_kernel(const int* __restrict__ counts,
                                                      int* __restrict__ bsums) {
  int t = blockIdx.x * 256 + threadIdx.x;
  int v = (t < N_NODES) ? counts[t] : 0;
#pragma unroll
  for (int off = 1; off < 64; off <<= 1) v += __shfl_xor(v, off, 64);
  __shared__ int ws[4];
  if ((threadIdx.x & 63) == 0) ws[threadIdx.x >> 6] = v;
  __syncthreads();
  if (threadIdx.x == 0) bsums[blockIdx.x] = ws[0] + ws[1] + ws[2] + ws[3];
}

// 2/3: exclusive scan of the 196 block sums (one 256-thread block)
__global__ __launch_bounds__(256) void scanb_kernel(const int* __restrict__ bsums,
                                                    int* __restrict__ boff) {
  __shared__ int s[256];
  int tid = threadIdx.x;
  int v = (tid < SCAN_BLOCKS) ? bsums[tid] : 0;
  s[tid] = v;
  __syncthreads();
  for (int off = 1; off < 256; off <<= 1) {
    int t = (tid >= off) ? s[tid - off] : 0;
    __syncthreads();
    s[tid] += t;
    __syncthreads();
  }
  boff[tid] = s[tid] - v;  // exclusive
}

// 3/3: per-block exclusive scan + global offset -> row_start, cursor
__global__ __launch_bounds__(256) void expand_kernel(const int* __restrict__ counts,
                                                     const int* __restrict__ boff,
                                                     int* __restrict__ row_start,
                                                     int* __restrict__ cursor) {
  int t = blockIdx.x * 256 + threadIdx.x;
  int tid = threadIdx.x;
  int v = (t < N_NODES) ? counts[t] : 0;
  __shared__ int s[256];
  s[tid] = v;
  __syncthreads();
  for (int off = 1; off < 256; off <<= 1) {
    int tv = (tid >= off) ? s[tid - off] : 0;
    __syncthreads();
    s[tid] += tv;
    __syncthreads();
  }
  int ex = boff[blockIdx.x] + s[tid] - v;
  if (t < N_NODES) {
    row_start[t] = ex;
    cursor[t] = ex;
  }
  if (t == N_NODES) row_start[N_NODES] = N_EDGES;
}

__global__ void fill_kernel(const int* __restrict__ rows, const int* __restrict__ cols,
                            const float* __restrict__ vals, int* cursor,
                            uint2* __restrict__ pairs) {
  int e = blockIdx.x * blockDim.x + threadIdx.x;
  if (e >= N_EDGES) return;
  int r = rows[e];
  int pos = atomicAdd(&cursor[r], 1);
  pairs[pos] = make_uint2((uint)cols[e], __float_as_uint(vals[e]));
}

// Modified weights, transposed + bf16: wtT[o][k], k = m*64+c, m in 0..3.
// Wt0=W0-W2, Wt1=W1-3W3, Wt2=2W2, Wt3=4W3.  w layout: [m][c][o].
__global__ __launch_bounds__(256) void wprep_kernel(const float* __restrict__ w,
                                                    ushort* __restrict__ wtT) {
  int t = blockIdx.x * 256 + threadIdx.x;
  if (t >= 64 * 256) return;
  int o = t >> 8, k = t & 255, m = k >> 6, c = k & 63;
  int idx = c * 64 + o;
  float v;
  if (m == 0)      v = w[idx] - w[2 * 4096 + idx];
  else if (m == 1) v = w[4096 + idx] - 3.0f * w[3 * 4096 + idx];
  else if (m == 2) v = 2.0f * w[2 * 4096 + idx];
  else             v = 4.0f * w[3 * 4096 + idx];
  wtT[t] = bf16one(v);
}

// f32 [b][node][64] -> bf16 interleaved [node][b][64] (word layout [node][128w])
__global__ __launch_bounds__(256) void cvt_interleave_kernel(const float* __restrict__ in,
                                                             uint* __restrict__ outw) {
  int t = blockIdx.x * 256 + threadIdx.x;  // 1.6M threads, 8 elems each
  if (t >= (BATCH * BN) / 8) return;
  int c8 = t & 7;
  int b = (t >> 3) & 3;
  int node = t >> 5;
  const float* p = in + (size_t)b * BN + (size_t)node * 64 + c8 * 8;
  float4 a = *reinterpret_cast<const float4*>(p);
  float4 bb = *reinterpret_cast<const float4*>(p + 4);
  uint4 r;
  r.x = pack_bf16(a.x, a.y);
  r.y = pack_bf16(a.z, a.w);
  r.z = pack_bf16(bb.x, bb.y);
  r.w = pack_bf16(bb.z, bb.w);
  *reinterpret_cast<uint4*>(outw + (size_t)node * 128 + b * 32 + c8 * 4) = r;
}

__device__ __forceinline__ void edge_fma(float acc[8], float v, const uint4& q) {
  acc[0] = fmaf(v, bf16lo(q.x), acc[0]);
  acc[1] = fmaf(v, bf16hi(q.x), acc[1]);
  acc[2] = fmaf(v, bf16lo(q.y), acc[2]);
  acc[3] = fmaf(v, bf16hi(q.y), acc[3]);
  acc[4] = fmaf(v, bf16lo(q.z), acc[4]);
  acc[5] = fmaf(v, bf16hi(q.z), acc[5]);
  acc[6] = fmaf(v, bf16lo(q.w), acc[6]);
  acc[7] = fmaf(v, bf16hi(q.w), acc[7]);
}

// dst = L * src, bf16 interleaved [node][b][ch]. One wave per dest row.
// Per edge: one contiguous 512B gather (32 lanes x 16B); lanes 0-31 = even
// edges, 32-63 = odd edges; 4-deep unroll per half; shfl fold at end.
__global__ __launch_bounds__(256) void spmm_bf16(const int* __restrict__ row_start,
                                                 const uint2* __restrict__ pairs,
                                                 const uint* __restrict__ src,
                                                 uint* __restrict__ dst) {
  int row = blockIdx.x * 4 + (threadIdx.x >> 6);
  int lane = threadIdx.x & 63;
  int half = lane >> 5;
  int hl = lane & 31;
  const uint* srcw = src + hl * 4;
  int s = row_start[row], e = row_start[row + 1];
  float acc[8];
#pragma unroll
  for (int j = 0; j < 8; ++j) acc[j] = 0.f;
  int i = s + half;
  for (; i + 6 < e; i += 8) {
    uint2 p0 = pairs[i];
    uint2 p1 = pairs[i + 2];
    uint2 p2 = pairs[i + 4];
    uint2 p3 = pairs[i + 6];
    uint4 q0 = *reinterpret_cast<const uint4*>(srcw + (size_t)p0.x * 128);
    uint4 q1 = *reinterpret_cast<const uint4*>(srcw + (size_t)p1.x * 128);
    uint4 q2 = *reinterpret_cast<const uint4*>(srcw + (size_t)p2.x * 128);
    uint4 q3 = *reinterpret_cast<const uint4*>(srcw + (size_t)p3.x * 128);
    edge_fma(acc, __uint_as_float(p0.y), q0);
    edge_fma(acc, __uint_as_float(p1.y), q1);
    edge_fma(acc, __uint_as_float(p2.y), q2);
    edge_fma(acc, __uint_as_float(p3.y), q3);
  }
  for (; i < e; i += 2) {
    uint2 p0 = pairs[i];
    uint4 q0 = *reinterpret_cast<const uint4*>(srcw + (size_t)p0.x * 128);
    edge_fma(acc, __uint_as_float(p0.y), q0);
  }
#pragma unroll
  for (int j = 0; j < 8; ++j) acc[j] += __shfl_xor(acc[j], 32, 64);
  if (half == 0) {
    uint4 r;
    r.x = pack_bf16(acc[0], acc[1]);
    r.y = pack_bf16(acc[2], acc[3]);
    r.z = pack_bf16(acc[4], acc[5]);
    r.w = pack_bf16(acc[6], acc[7]);
    *reinterpret_cast<uint4*>(dst + (size_t)row * 128 + hl * 4) = r;
  }
}

// out = relu(bias + [x|S1|S2|S3] @ WtT^T), MFMA 16x16x32 bf16.
// Block = 4 waves; wave = 16 rows x 64 out-channels; K = 256 (8 steps).
__global__ __launch_bounds__(256) void gemm4_mfma(
    const uint* __restrict__ A0, const uint* __restrict__ A1,
    const uint* __restrict__ A2, const uint* __restrict__ A3,
    const uint* __restrict__ wtT,   // [64][128] words (bf16 [64][256])
    const float* __restrict__ bias, float* __restrict__ out) {
  __shared__ uint WS[64 * 132];
  __shared__ float bias_s[64];
  for (int w = threadIdx.x; w < 8192; w += 256)
    WS[(w >> 7) * 132 + (w & 127)] = wtT[w];
  if (threadIdx.x < 64) bias_s[threadIdx.x] = bias[threadIdx.x];
  __syncthreads();

  const int lane = threadIdx.x & 63;
  const int wv = threadIdx.x >> 6;
  const int r0 = blockIdx.x * 64 + wv * 16;
  const int c16 = lane & 15;
  const int hi = lane >> 4;

  const size_t arow = (size_t)(r0 + c16) * 32 + hi * 4;

  f32x4 acc[4] = {{0.f, 0.f, 0.f, 0.f}, {0.f, 0.f, 0.f, 0.f},
                  {0.f, 0.f, 0.f, 0.f}, {0.f, 0.f, 0.f, 0.f}};

#pragma unroll
  for (int ks = 0; ks < 8; ++ks) {
    const uint* ab = (ks >> 1) == 0 ? A0 : (ks >> 1) == 1 ? A1
                   : (ks >> 1) == 2 ? A2 : A3;
    uint4 av = *reinterpret_cast<const uint4*>(ab + arow + (ks & 1) * 16);
    short8 afrag = __builtin_bit_cast(short8, av);
#pragma unroll
    for (int nt = 0; nt < 4; ++nt) {
      uint4 bv = *reinterpret_cast<const uint4*>(
          &WS[(nt * 16 + c16) * 132 + ks * 16 + hi * 4]);
      short8 bfrag = __builtin_bit_cast(short8, bv);
      acc[nt] = __builtin_amdgcn_mfma_f32_16x16x32_bf16(afrag, bfrag, acc[nt], 0, 0, 0);
    }
  }

  // C/D layout: col = lane&15, row = (lane>>4)*4 + i  [verified m89/m91]
#pragma unroll
  for (int nt = 0; nt < 4; ++nt) {
#pragma unroll
    for (int i = 0; i < 4; ++i) {
      int row = r0 + hi * 4 + i;
      int node = row >> 2, b = row & 3;
      int col = nt * 16 + c16;
      float v = acc[nt][i] + bias_s[col];
      out[(size_t)b * BN + (size_t)node * 64 + col] = fmaxf(v, 0.f);
    }
  }
}

extern "C" void kernel_launch(void* const* d_in, const int* in_sizes, int n_in,
                              void* d_out, int out_size, void* d_ws, size_t ws_size,
                              hipStream_t stream) {
  const float* x        = (const float*)d_in[0];
  const int*   lap_rows = (const int*)d_in[1];
  const int*   lap_cols = (const int*)d_in[2];
  const float* lap_vals = (const float*)d_in[3];
  const float* weights  = (const float*)d_in[4];  // [4][64][64]
  const float* bias     = (const float*)d_in[5];
  float* out = (float*)d_out;

  char* ws = (char*)d_ws;
  size_t off = 0;
  auto alloc = [&](size_t bytes) {
    void* p = ws + off;
    off += (bytes + 255) & ~(size_t)255;
    return p;
  };
  int*    counts    = (int*)alloc((size_t)N_NODES * 4);
  int*    bsums     = (int*)alloc((size_t)256 * 4);
  int*    boff      = (int*)alloc((size_t)256 * 4);
  int*    row_start = (int*)alloc((size_t)(N_NODES + 1) * 4);
  int*    cursor    = (int*)alloc((size_t)N_NODES * 4);
  uint2*  pairs     = (uint2*)alloc((size_t)N_EDGES * 8);
  ushort* wtT       = (ushort*)alloc((size_t)64 * 256 * 2);
  uint*   xb        = (uint*)alloc((size_t)ROWS_TOTAL * 32 * 4);  // 25.6MB each
  uint*   S1        = (uint*)alloc((size_t)ROWS_TOTAL * 32 * 4);
  uint*   S2        = (uint*)alloc((size_t)ROWS_TOTAL * 32 * 4);
  uint*   S3        = (uint*)alloc((size_t)ROWS_TOTAL * 32 * 4);
  (void)ws_size; (void)in_sizes; (void)n_in; (void)out_size;

  // Weight prep + x->bf16 interleave + CSR build (parallel scan)
  wprep_kernel<<<64, 256, 0, stream>>>(weights, wtT);
  cvt_interleave_kernel<<<(BATCH * BN / 8 + 255) / 256, 256, 0, stream>>>(x, xb);
  hipMemsetAsync(counts, 0, (size_t)N_NODES * 4, stream);
  hist_kernel<<<(N_EDGES + 255) / 256, 256, 0, stream>>>(lap_rows, counts);
  partial_kernel<<<SCAN_BLOCKS, 256, 0, stream>>>(counts, bsums);
  scanb_kernel<<<1, 256, 0, stream>>>(bsums, boff);
  expand_kernel<<<SCAN_BLOCKS, 256, 0, stream>>>(counts, boff, row_start, cursor);
  fill_kernel<<<(N_EDGES + 255) / 256, 256, 0, stream>>>(lap_rows, lap_cols, lap_vals,
                                                         cursor, pairs);

  const int spmm_blocks = N_NODES / 4;  // 12500, one wave per row

  // S1 = L x ; S2 = L S1 ; S3 = L S2
  spmm_bf16<<<spmm_blocks, 256, 0, stream>>>(row_start, pairs, xb, S1);
  spmm_bf16<<<spmm_blocks, 256, 0, stream>>>(row_start, pairs, S1, S2);
  spmm_bf16<<<spmm_blocks, 256, 0, stream>>>(row_start, pairs, S2, S3);
  // out = relu(bias + x@Wt0 + S1@Wt1 + S2@Wt2 + S3@Wt3)
  gemm4_mfma<<<ROWS_TOTAL / 64, 256, 0, stream>>>(xb, S1, S2, S3, (const uint*)wtT,
                                                  bias, out);
}

// Round 7
// 266.419 us; speedup vs baseline: 4.3679x; 1.1340x over previous
//
#include <hip/hip_runtime.h>

// ChebyshevGCNN: out = relu(bias + x@W0 + T1@W1 + T2@W2 + T3@W3)
// Reassociated: S1=Lx, S2=LS1, S3=LS2;  T2=2S2-x, T3=4S3-3S1
//   => out = relu(bias + x@(W0-W2) + S1@(W1-3W3) + S2@(2W2) + S3@(4W3))
// Round 7: CSR build via two-level LDS-binned counting sort (kills the 52MB
// write-amplified random scatter); spmm gather ladder 8/4/1 per half-wave.

#define N_NODES 50000
#define N_EDGES 800000
#define BATCH 4
#define CH 64
#define BN (N_NODES * CH)             // elems per batch matrix (out layout)
#define ROWS_TOTAL (BATCH * N_NODES)  // 200,000
#define NB 782                        // buckets of 64 rows: 782*64 = 50048
#define EPB 8192                      // edges per block in bucket passes
#define SCT_BLOCKS ((N_EDGES + EPB - 1) / EPB)  // 98

typedef unsigned int uint;
typedef unsigned short ushort;
typedef __attribute__((ext_vector_type(8))) short short8;   // 8 x bf16
typedef __attribute__((ext_vector_type(4))) float f32x4;

__device__ __forceinline__ float bf16lo(uint u) { return __uint_as_float(u << 16); }
__device__ __forceinline__ float bf16hi(uint u) { return __uint_as_float(u & 0xffff0000u); }
__device__ __forceinline__ uint pack_bf16(float lo, float hi) {
  uint a = __float_as_uint(lo);
  uint b = __float_as_uint(hi);
  a = (a + 0x7fffu + ((a >> 16) & 1u)) >> 16;  // RN-even
  b = (b + 0x7fffu + ((b >> 16) & 1u)) >> 16;
  return a | (b << 16);
}
__device__ __forceinline__ ushort bf16one(float x) {
  uint a = __float_as_uint(x);
  a = (a + 0x7fffu + ((a >> 16) & 1u)) >> 16;
  return (ushort)a;
}

// ---------------- CSR build: two-level counting sort ----------------
// 1/4: per-bucket histogram (LDS pre-aggregated)
__global__ __launch_bounds__(256) void bucket_hist(const int* __restrict__ rows,
                                                   int* __restrict__ gcounts) {
  __shared__ int h[NB];
  for (int b = threadIdx.x; b < NB; b += 256) h[b] = 0;
  __syncthreads();
  int base_e = blockIdx.x * EPB;
#pragma unroll
  for (int j = 0; j < EPB / 256; ++j) {
    int e = base_e + j * 256 + threadIdx.x;
    if (e < N_EDGES) atomicAdd(&h[rows[e] >> 6], 1);
  }
  __syncthreads();
  for (int b = threadIdx.x; b < NB; b += 256)
    if (h[b]) atomicAdd(&gcounts[b], h[b]);
}

// 2/4: exclusive scan of bucket counts -> bucket_base[NB+1], gcursor[NB]
__global__ __launch_bounds__(1024) void bucket_scan(const int* __restrict__ gcounts,
                                                    int* __restrict__ bucket_base,
                                                    int* __restrict__ gcursor) {
  __shared__ int s[1024];
  int t = threadIdx.x;
  int v = (t < NB) ? gcounts[t] : 0;
  s[t] = v;
  __syncthreads();
  for (int off = 1; off < 1024; off <<= 1) {
    int tv = (t >= off) ? s[t - off] : 0;
    __syncthreads();
    s[t] += tv;
    __syncthreads();
  }
  int ex = s[t] - v;
  if (t < NB) { bucket_base[t] = ex; gcursor[t] = ex; }
  if (t == NB) bucket_base[NB] = N_EDGES;
}

// 3/4: scatter edges into bucket segments (block-contiguous ranges -> good
// write-line locality). Staged word0 = col | (row&63)<<20.
__global__ __launch_bounds__(256) void bucket_scatter(const int* __restrict__ rows,
                                                      const int* __restrict__ cols,
                                                      const float* __restrict__ vals,
                                                      int* __restrict__ gcursor,
                                                      uint2* __restrict__ staging) {
  __shared__ int lcur[NB];
  for (int b = threadIdx.x; b < NB; b += 256) lcur[b] = 0;
  __syncthreads();
  int base_e = blockIdx.x * EPB;
#pragma unroll
  for (int j = 0; j < EPB / 256; ++j) {
    int e = base_e + j * 256 + threadIdx.x;
    if (e < N_EDGES) atomicAdd(&lcur[rows[e] >> 6], 1);
  }
  __syncthreads();
  for (int b = threadIdx.x; b < NB; b += 256) {
    int c = lcur[b];
    lcur[b] = (c > 0) ? atomicAdd(&gcursor[b], c) : 0;
  }
  __syncthreads();
#pragma unroll
  for (int j = 0; j < EPB / 256; ++j) {
    int e = base_e + j * 256 + threadIdx.x;
    if (e < N_EDGES) {
      int r = rows[e];
      int pos = atomicAdd(&lcur[r >> 6], 1);
      staging[pos] = make_uint2((uint)cols[e] | ((uint)(r & 63) << 20),
                                __float_as_uint(vals[e]));
    }
  }
}

// 4/4: within each bucket, group by exact row; emit pairs + row_start.
__global__ __launch_bounds__(256) void bucket_finalize(const int* __restrict__ bucket_base,
                                                       const uint2* __restrict__ staging,
                                                       uint2* __restrict__ pairs,
                                                       int* __restrict__ row_start) {
  int b = blockIdx.x;
  int seg0 = bucket_base[b], seg1 = bucket_base[b + 1];
  __shared__ int hist[64];
  __shared__ int cur[64];
  if (threadIdx.x < 64) hist[threadIdx.x] = 0;
  __syncthreads();
  for (int i = seg0 + threadIdx.x; i < seg1; i += 256)
    atomicAdd(&hist[staging[i].x >> 20], 1);
  __syncthreads();
  if (threadIdx.x < 64) {
    int v = hist[threadIdx.x];
    int sc = v;
#pragma unroll
    for (int off = 1; off < 64; off <<= 1) {
      int t = __shfl_up(sc, off, 64);
      if (threadIdx.x >= (unsigned)off) sc += t;
    }
    int start = seg0 + sc - v;  // exclusive
    cur[threadIdx.x] = start;
    int r = b * 64 + threadIdx.x;
    if (r < N_NODES) row_start[r] = start;
    if (r == N_NODES) row_start[N_NODES] = N_EDGES;
  }
  __syncthreads();
  for (int i = seg0 + threadIdx.x; i < seg1; i += 256) {
    uint2 eu = staging[i];
    int rl = eu.x >> 20;
    int pos = atomicAdd(&cur[rl], 1);
    pairs[pos] = make_uint2(eu.x & 0xFFFFFu, eu.y);
  }
}

// Modified weights, transposed + bf16: wtT[o][k], k = m*64+c, m in 0..3.
// Wt0=W0-W2, Wt1=W1-3W3, Wt2=2W2, Wt3=4W3.  w layout: [m][c][o].
__global__ __launch_bounds__(256) void wprep_kernel(const float* __restrict__ w,
                                                    ushort* __restrict__ wtT) {
  int t = blockIdx.x * 256 + threadIdx.x;
  if (t >= 64 * 256) return;
  int o = t >> 8, k = t & 255, m = k >> 6, c = k & 63;
  int idx = c * 64 + o;
  float v;
  if (m == 0)      v = w[idx] - w[2 * 4096 + idx];
  else if (m == 1) v = w[4096 + idx] - 3.0f * w[3 * 4096 + idx];
  else if (m == 2) v = 2.0f * w[2 * 4096 + idx];
  else             v = 4.0f * w[3 * 4096 + idx];
  wtT[t] = bf16one(v);
}

// f32 [b][node][64] -> bf16 interleaved [node][b][64] (word layout [node][128w])
__global__ __launch_bounds__(256) void cvt_interleave_kernel(const float* __restrict__ in,
                                                             uint* __restrict__ outw) {
  int t = blockIdx.x * 256 + threadIdx.x;  // 8 elems each
  if (t >= (BATCH * BN) / 8) return;
  int c8 = t & 7;
  int b = (t >> 3) & 3;
  int node = t >> 5;
  const float* p = in + (size_t)b * BN + (size_t)node * 64 + c8 * 8;
  float4 a = *reinterpret_cast<const float4*>(p);
  float4 bb = *reinterpret_cast<const float4*>(p + 4);
  uint4 r;
  r.x = pack_bf16(a.x, a.y);
  r.y = pack_bf16(a.z, a.w);
  r.z = pack_bf16(bb.x, bb.y);
  r.w = pack_bf16(bb.z, bb.w);
  *reinterpret_cast<uint4*>(outw + (size_t)node * 128 + b * 32 + c8 * 4) = r;
}

__device__ __forceinline__ void edge_fma(float acc[8], float v, const uint4& q) {
  acc[0] = fmaf(v, bf16lo(q.x), acc[0]);
  acc[1] = fmaf(v, bf16hi(q.x), acc[1]);
  acc[2] = fmaf(v, bf16lo(q.y), acc[2]);
  acc[3] = fmaf(v, bf16hi(q.y), acc[3]);
  acc[4] = fmaf(v, bf16lo(q.z), acc[4]);
  acc[5] = fmaf(v, bf16hi(q.z), acc[5]);
  acc[6] = fmaf(v, bf16lo(q.w), acc[6]);
  acc[7] = fmaf(v, bf16hi(q.w), acc[7]);
}

// dst = L * src, bf16 interleaved [node][b][ch]. One wave per dest row.
// Per edge: one contiguous 512B gather (32 lanes x 16B); lanes 0-31 = even
// edges, 32-63 = odd edges; 8/4/1 unroll ladder per half; shfl fold at end.
__global__ __launch_bounds__(256) void spmm_bf16(const int* __restrict__ row_start,
                                                 const uint2* __restrict__ pairs,
                                                 const uint* __restrict__ src,
                                                 uint* __restrict__ dst) {
  int row = blockIdx.x * 4 + (threadIdx.x >> 6);
  int lane = threadIdx.x & 63;
  int half = lane >> 5;
  int hl = lane & 31;
  const uint* srcw = src + hl * 4;
  int s = row_start[row], e = row_start[row + 1];
  float acc[8];
#pragma unroll
  for (int j = 0; j < 8; ++j) acc[j] = 0.f;
  int i = s + half;
  for (; i + 14 < e; i += 16) {
    uint2 p[8];
#pragma unroll
    for (int u = 0; u < 8; ++u) p[u] = pairs[i + 2 * u];
    uint4 q[8];
#pragma unroll
    for (int u = 0; u < 8; ++u)
      q[u] = *reinterpret_cast<const uint4*>(srcw + (size_t)p[u].x * 128);
#pragma unroll
    for (int u = 0; u < 8; ++u) edge_fma(acc, __uint_as_float(p[u].y), q[u]);
  }
  for (; i + 6 < e; i += 8) {
    uint2 p[4];
#pragma unroll
    for (int u = 0; u < 4; ++u) p[u] = pairs[i + 2 * u];
    uint4 q[4];
#pragma unroll
    for (int u = 0; u < 4; ++u)
      q[u] = *reinterpret_cast<const uint4*>(srcw + (size_t)p[u].x * 128);
#pragma unroll
    for (int u = 0; u < 4; ++u) edge_fma(acc, __uint_as_float(p[u].y), q[u]);
  }
  for (; i < e; i += 2) {
    uint2 p0 = pairs[i];
    uint4 q0 = *reinterpret_cast<const uint4*>(srcw + (size_t)p0.x * 128);
    edge_fma(acc, __uint_as_float(p0.y), q0);
  }
#pragma unroll
  for (int j = 0; j < 8; ++j) acc[j] += __shfl_xor(acc[j], 32, 64);
  if (half == 0) {
    uint4 r;
    r.x = pack_bf16(acc[0], acc[1]);
    r.y = pack_bf16(acc[2], acc[3]);
    r.z = pack_bf16(acc[4], acc[5]);
    r.w = pack_bf16(acc[6], acc[7]);
    *reinterpret_cast<uint4*>(dst + (size_t)row * 128 + hl * 4) = r;
  }
}

// out = relu(bias + [x|S1|S2|S3] @ WtT^T), MFMA 16x16x32 bf16.
// Block = 4 waves; wave = 16 rows x 64 out-channels; K = 256 (8 steps).
__global__ __launch_bounds__(256) void gemm4_mfma(
    const uint* __restrict__ A0, const uint* __restrict__ A1,
    const uint* __restrict__ A2, const uint* __restrict__ A3,
    const uint* __restrict__ wtT,   // [64][128] words (bf16 [64][256])
    const float* __restrict__ bias, float* __restrict__ out) {
  __shared__ uint WS[64 * 132];
  __shared__ float bias_s[64];
  for (int w = threadIdx.x; w < 8192; w += 256)
    WS[(w >> 7) * 132 + (w & 127)] = wtT[w];
  if (threadIdx.x < 64) bias_s[threadIdx.x] = bias[threadIdx.x];
  __syncthreads();

  const int lane = threadIdx.x & 63;
  const int wv = threadIdx.x >> 6;
  const int r0 = blockIdx.x * 64 + wv * 16;
  const int c16 = lane & 15;
  const int hi = lane >> 4;

  const size_t arow = (size_t)(r0 + c16) * 32 + hi * 4;

  f32x4 acc[4] = {{0.f, 0.f, 0.f, 0.f}, {0.f, 0.f, 0.f, 0.f},
                  {0.f, 0.f, 0.f, 0.f}, {0.f, 0.f, 0.f, 0.f}};

#pragma unroll
  for (int ks = 0; ks < 8; ++ks) {
    const uint* ab = (ks >> 1) == 0 ? A0 : (ks >> 1) == 1 ? A1
                   : (ks >> 1) == 2 ? A2 : A3;
    uint4 av = *reinterpret_cast<const uint4*>(ab + arow + (ks & 1) * 16);
    short8 afrag = __builtin_bit_cast(short8, av);
#pragma unroll
    for (int nt = 0; nt < 4; ++nt) {
      uint4 bv = *reinterpret_cast<const uint4*>(
          &WS[(nt * 16 + c16) * 132 + ks * 16 + hi * 4]);
      short8 bfrag = __builtin_bit_cast(short8, bv);
      acc[nt] = __builtin_amdgcn_mfma_f32_16x16x32_bf16(afrag, bfrag, acc[nt], 0, 0, 0);
    }
  }

  // C/D layout: col = lane&15, row = (lane>>4)*4 + i  [verified m89/m91]
#pragma unroll
  for (int nt = 0; nt < 4; ++nt) {
#pragma unroll
    for (int i = 0; i < 4; ++i) {
      int row = r0 + hi * 4 + i;
      int node = row >> 2, b = row & 3;
      int col = nt * 16 + c16;
      float v = acc[nt][i] + bias_s[col];
      out[(size_t)b * BN + (size_t)node * 64 + col] = fmaxf(v, 0.f);
    }
  }
}

extern "C" void kernel_launch(void* const* d_in, const int* in_sizes, int n_in,
                              void* d_out, int out_size, void* d_ws, size_t ws_size,
                              hipStream_t stream) {
  const float* x        = (const float*)d_in[0];
  const int*   lap_rows = (const int*)d_in[1];
  const int*   lap_cols = (const int*)d_in[2];
  const float* lap_vals = (const float*)d_in[3];
  const float* weights  = (const float*)d_in[4];  // [4][64][64]
  const float* bias     = (const float*)d_in[5];
  float* out = (float*)d_out;

  char* ws = (char*)d_ws;
  size_t off = 0;
  auto alloc = [&](size_t bytes) {
    void* p = ws + off;
    off += (bytes + 255) & ~(size_t)255;
    return p;
  };
  int*    gcounts     = (int*)alloc((size_t)NB * 4);
  int*    gcursor     = (int*)alloc((size_t)NB * 4);
  int*    bucket_base = (int*)alloc((size_t)(NB + 1) * 4);
  int*    row_start   = (int*)alloc((size_t)(N_NODES + 1) * 4);
  uint2*  staging     = (uint2*)alloc((size_t)N_EDGES * 8);
  uint2*  pairs       = (uint2*)alloc((size_t)N_EDGES * 8);
  ushort* wtT         = (ushort*)alloc((size_t)64 * 256 * 2);
  uint*   xb          = (uint*)alloc((size_t)ROWS_TOTAL * 32 * 4);  // 25.6MB each
  uint*   S1          = (uint*)alloc((size_t)ROWS_TOTAL * 32 * 4);
  uint*   S2          = (uint*)alloc((size_t)ROWS_TOTAL * 32 * 4);
  uint*   S3          = (uint*)alloc((size_t)ROWS_TOTAL * 32 * 4);
  (void)ws_size; (void)in_sizes; (void)n_in; (void)out_size;

  // Weight prep + x->bf16 interleave + CSR build (counting sort)
  wprep_kernel<<<64, 256, 0, stream>>>(weights, wtT);
  cvt_interleave_kernel<<<(BATCH * BN / 8 + 255) / 256, 256, 0, stream>>>(x, xb);
  hipMemsetAsync(gcounts, 0, (size_t)NB * 4, stream);
  bucket_hist<<<SCT_BLOCKS, 256, 0, stream>>>(lap_rows, gcounts);
  bucket_scan<<<1, 1024, 0, stream>>>(gcounts, bucket_base, gcursor);
  bucket_scatter<<<SCT_BLOCKS, 256, 0, stream>>>(lap_rows, lap_cols, lap_vals,
                                                 gcursor, staging);
  bucket_finalize<<<NB, 256, 0, stream>>>(bucket_base, staging, pairs, row_start);

  const int spmm_blocks = N_NODES / 4;  // 12500, one wave per row

  // S1 = L x ; S2 = L S1 ; S3 = L S2
  spmm_bf16<<<spmm_blocks, 256, 0, stream>>>(row_start, pairs, xb, S1);
  spmm_bf16<<<spmm_blocks, 256, 0, stream>>>(row_start, pairs, S1, S2);
  spmm_bf16<<<spmm_blocks, 256, 0, stream>>>(row_start, pairs, S2, S3);
  // out = relu(bias + x@Wt0 + S1@Wt1 + S2@Wt2 + S3@Wt3)
  gemm4_mfma<<<ROWS_TOTAL / 64, 256, 0, stream>>>(xb, S1, S2, S3, (const uint*)wtT,
                                                  bias, out);
}

// Round 8
// 227.741 us; speedup vs baseline: 5.1098x; 1.1698x over previous
//
#include <hip/hip_runtime.h>

// ChebyshevGCNN: out = relu(bias + x@W0 + T1@W1 + T2@W2 + T3@W3)
// Reassociated: S1=Lx, S2=LS1, S3=LS2;  T2=2S2-x, T3=4S3-3S1
//   => out = relu(bias + x@(W0-W2) + S1@(W1-3W3) + S2@(2W2) + S3@(4W3))
// Round 8: S1/S2 stored as int8 with per-node block scale (halves the
// dominant gather fetch for passes 2+3); gemm4 dequantizes A-frags in-register
// (no bf16 copies of S1/S2). x and S3 remain bf16.

#define N_NODES 50000
#define N_EDGES 800000
#define BATCH 4
#define CH 64
#define BN (N_NODES * CH)             // elems per batch matrix (out layout)
#define ROWS_TOTAL (BATCH * N_NODES)  // 200,000
#define NB 782                        // buckets of 64 rows: 782*64 = 50048
#define EPB 8192                      // edges per block in bucket passes
#define SCT_BLOCKS ((N_EDGES + EPB - 1) / EPB)  // 98

typedef unsigned int uint;
typedef unsigned short ushort;
typedef unsigned char uchar;
typedef __attribute__((ext_vector_type(8))) short short8;   // 8 x bf16
typedef __attribute__((ext_vector_type(4))) float f32x4;

__device__ __forceinline__ float bf16lo(uint u) { return __uint_as_float(u << 16); }
__device__ __forceinline__ float bf16hi(uint u) { return __uint_as_float(u & 0xffff0000u); }
__device__ __forceinline__ uint pack_bf16(float lo, float hi) {
  uint a = __float_as_uint(lo);
  uint b = __float_as_uint(hi);
  a = (a + 0x7fffu + ((a >> 16) & 1u)) >> 16;  // RN-even
  b = (b + 0x7fffu + ((b >> 16) & 1u)) >> 16;
  return a | (b << 16);
}
__device__ __forceinline__ ushort bf16one(float x) {
  uint a = __float_as_uint(x);
  a = (a + 0x7fffu + ((a >> 16) & 1u)) >> 16;
  return (ushort)a;
}

// ---------------- CSR build: two-level counting sort ----------------
__global__ __launch_bounds__(256) void bucket_hist(const int* __restrict__ rows,
                                                   int* __restrict__ gcounts) {
  __shared__ int h[NB];
  for (int b = threadIdx.x; b < NB; b += 256) h[b] = 0;
  __syncthreads();
  int base_e = blockIdx.x * EPB;
#pragma unroll
  for (int j = 0; j < EPB / 256; ++j) {
    int e = base_e + j * 256 + threadIdx.x;
    if (e < N_EDGES) atomicAdd(&h[rows[e] >> 6], 1);
  }
  __syncthreads();
  for (int b = threadIdx.x; b < NB; b += 256)
    if (h[b]) atomicAdd(&gcounts[b], h[b]);
}

__global__ __launch_bounds__(1024) void bucket_scan(const int* __restrict__ gcounts,
                                                    int* __restrict__ bucket_base,
                                                    int* __restrict__ gcursor) {
  __shared__ int s[1024];
  int t = threadIdx.x;
  int v = (t < NB) ? gcounts[t] : 0;
  s[t] = v;
  __syncthreads();
  for (int off = 1; off < 1024; off <<= 1) {
    int tv = (t >= off) ? s[t - off] : 0;
    __syncthreads();
    s[t] += tv;
    __syncthreads();
  }
  int ex = s[t] - v;
  if (t < NB) { bucket_base[t] = ex; gcursor[t] = ex; }
  if (t == NB) bucket_base[NB] = N_EDGES;
}

__global__ __launch_bounds__(256) void bucket_scatter(const int* __restrict__ rows,
                                                      const int* __restrict__ cols,
                                                      const float* __restrict__ vals,
                                                      int* __restrict__ gcursor,
                                                      uint2* __restrict__ staging) {
  __shared__ int lcur[NB];
  for (int b = threadIdx.x; b < NB; b += 256) lcur[b] = 0;
  __syncthreads();
  int base_e = blockIdx.x * EPB;
#pragma unroll
  for (int j = 0; j < EPB / 256; ++j) {
    int e = base_e + j * 256 + threadIdx.x;
    if (e < N_EDGES) atomicAdd(&lcur[rows[e] >> 6], 1);
  }
  __syncthreads();
  for (int b = threadIdx.x; b < NB; b += 256) {
    int c = lcur[b];
    lcur[b] = (c > 0) ? atomicAdd(&gcursor[b], c) : 0;
  }
  __syncthreads();
#pragma unroll
  for (int j = 0; j < EPB / 256; ++j) {
    int e = base_e + j * 256 + threadIdx.x;
    if (e < N_EDGES) {
      int r = rows[e];
      int pos = atomicAdd(&lcur[r >> 6], 1);
      staging[pos] = make_uint2((uint)cols[e] | ((uint)(r & 63) << 20),
                                __float_as_uint(vals[e]));
    }
  }
}

__global__ __launch_bounds__(256) void bucket_finalize(const int* __restrict__ bucket_base,
                                                       const uint2* __restrict__ staging,
                                                       uint2* __restrict__ pairs,
                                                       int* __restrict__ row_start) {
  int b = blockIdx.x;
  int seg0 = bucket_base[b], seg1 = bucket_base[b + 1];
  __shared__ int hist[64];
  __shared__ int cur[64];
  if (threadIdx.x < 64) hist[threadIdx.x] = 0;
  __syncthreads();
  for (int i = seg0 + threadIdx.x; i < seg1; i += 256)
    atomicAdd(&hist[staging[i].x >> 20], 1);
  __syncthreads();
  if (threadIdx.x < 64) {
    int v = hist[threadIdx.x];
    int sc = v;
#pragma unroll
    for (int off = 1; off < 64; off <<= 1) {
      int t = __shfl_up(sc, off, 64);
      if (threadIdx.x >= (unsigned)off) sc += t;
    }
    int start = seg0 + sc - v;  // exclusive
    cur[threadIdx.x] = start;
    int r = b * 64 + threadIdx.x;
    if (r < N_NODES) row_start[r] = start;
    if (r == N_NODES) row_start[N_NODES] = N_EDGES;
  }
  __syncthreads();
  for (int i = seg0 + threadIdx.x; i < seg1; i += 256) {
    uint2 eu = staging[i];
    int rl = eu.x >> 20;
    int pos = atomicAdd(&cur[rl], 1);
    pairs[pos] = make_uint2(eu.x & 0xFFFFFu, eu.y);
  }
}

// Modified weights, transposed + bf16: wtT[o][k], k = m*64+c, m in 0..3.
__global__ __launch_bounds__(256) void wprep_kernel(const float* __restrict__ w,
                                                    ushort* __restrict__ wtT) {
  int t = blockIdx.x * 256 + threadIdx.x;
  if (t >= 64 * 256) return;
  int o = t >> 8, k = t & 255, m = k >> 6, c = k & 63;
  int idx = c * 64 + o;
  float v;
  if (m == 0)      v = w[idx] - w[2 * 4096 + idx];
  else if (m == 1) v = w[4096 + idx] - 3.0f * w[3 * 4096 + idx];
  else if (m == 2) v = 2.0f * w[2 * 4096 + idx];
  else             v = 4.0f * w[3 * 4096 + idx];
  wtT[t] = bf16one(v);
}

// f32 [b][node][64] -> bf16 interleaved [node][b][64] (word layout [node][128w])
__global__ __launch_bounds__(256) void cvt_interleave_kernel(const float* __restrict__ in,
                                                             uint* __restrict__ outw) {
  int t = blockIdx.x * 256 + threadIdx.x;  // 8 elems each
  if (t >= (BATCH * BN) / 8) return;
  int c8 = t & 7;
  int b = (t >> 3) & 3;
  int node = t >> 5;
  const float* p = in + (size_t)b * BN + (size_t)node * 64 + c8 * 8;
  float4 a = *reinterpret_cast<const float4*>(p);
  float4 bb = *reinterpret_cast<const float4*>(p + 4);
  uint4 r;
  r.x = pack_bf16(a.x, a.y);
  r.y = pack_bf16(a.z, a.w);
  r.z = pack_bf16(bb.x, bb.y);
  r.w = pack_bf16(bb.z, bb.w);
  *reinterpret_cast<uint4*>(outw + (size_t)node * 128 + b * 32 + c8 * 4) = r;
}

__device__ __forceinline__ void edge_fma(float acc[8], float v, const uint4& q) {
  acc[0] = fmaf(v, bf16lo(q.x), acc[0]);
  acc[1] = fmaf(v, bf16hi(q.x), acc[1]);
  acc[2] = fmaf(v, bf16lo(q.y), acc[2]);
  acc[3] = fmaf(v, bf16hi(q.y), acc[3]);
  acc[4] = fmaf(v, bf16lo(q.z), acc[4]);
  acc[5] = fmaf(v, bf16hi(q.z), acc[5]);
  acc[6] = fmaf(v, bf16lo(q.w), acc[6]);
  acc[7] = fmaf(v, bf16hi(q.w), acc[7]);
}

__device__ __forceinline__ void edge_fma_i8(float acc[8], float m, const uint2& q) {
  acc[0] = fmaf(m, (float)((int)(q.x << 24) >> 24), acc[0]);
  acc[1] = fmaf(m, (float)((int)(q.x << 16) >> 24), acc[1]);
  acc[2] = fmaf(m, (float)((int)(q.x <<  8) >> 24), acc[2]);
  acc[3] = fmaf(m, (float)((int)q.x >> 24),         acc[3]);
  acc[4] = fmaf(m, (float)((int)(q.y << 24) >> 24), acc[4]);
  acc[5] = fmaf(m, (float)((int)(q.y << 16) >> 24), acc[5]);
  acc[6] = fmaf(m, (float)((int)(q.y <<  8) >> 24), acc[6]);
  acc[7] = fmaf(m, (float)((int)q.y >> 24),         acc[7]);
}

// dst = L * src, one wave per dest node row (4 batches x 64 ch = 256 vals).
// READ_I8: gather 256B/edge int8 + per-node scale (folded into multiplier);
// else gather 512B/edge bf16. WRITE_I8: emit int8 + per-node scale (max/127);
// else emit bf16. Lanes 0-31 even edges, 32-63 odd; shfl fold at end.
template <int READ_I8, int WRITE_I8>
__global__ __launch_bounds__(256) void spmm_kernel(
    const int* __restrict__ row_start, const uint2* __restrict__ pairs,
    const uint* __restrict__ src_bf, const uchar* __restrict__ src_i8,
    const float* __restrict__ src_sc, uint* __restrict__ dst_bf,
    uchar* __restrict__ dst_i8, float* __restrict__ dst_sc) {
  int row = blockIdx.x * 4 + (threadIdx.x >> 6);
  int lane = threadIdx.x & 63;
  int half = lane >> 5;
  int hl = lane & 31;
  int s = row_start[row], e = row_start[row + 1];
  float acc[8];
#pragma unroll
  for (int j = 0; j < 8; ++j) acc[j] = 0.f;
  int i = s + half;
  if (READ_I8) {
    const uchar* sb = src_i8 + hl * 8;
    for (; i + 6 < e; i += 8) {
      uint2 p[4];
#pragma unroll
      for (int u = 0; u < 4; ++u) p[u] = pairs[i + 2 * u];
      uint2 q[4];
      float m[4];
#pragma unroll
      for (int u = 0; u < 4; ++u) {
        q[u] = *reinterpret_cast<const uint2*>(sb + (size_t)p[u].x * 256);
        m[u] = __uint_as_float(p[u].y) * src_sc[p[u].x];
      }
#pragma unroll
      for (int u = 0; u < 4; ++u) edge_fma_i8(acc, m[u], q[u]);
    }
    for (; i < e; i += 2) {
      uint2 p0 = pairs[i];
      uint2 q0 = *reinterpret_cast<const uint2*>(sb + (size_t)p0.x * 256);
      edge_fma_i8(acc, __uint_as_float(p0.y) * src_sc[p0.x], q0);
    }
  } else {
    const uint* sw = src_bf + hl * 4;
    for (; i + 6 < e; i += 8) {
      uint2 p[4];
#pragma unroll
      for (int u = 0; u < 4; ++u) p[u] = pairs[i + 2 * u];
      uint4 q[4];
#pragma unroll
      for (int u = 0; u < 4; ++u)
        q[u] = *reinterpret_cast<const uint4*>(sw + (size_t)p[u].x * 128);
#pragma unroll
      for (int u = 0; u < 4; ++u) edge_fma(acc, __uint_as_float(p[u].y), q[u]);
    }
    for (; i < e; i += 2) {
      uint2 p0 = pairs[i];
      uint4 q0 = *reinterpret_cast<const uint4*>(sw + (size_t)p0.x * 128);
      edge_fma(acc, __uint_as_float(p0.y), q0);
    }
  }
#pragma unroll
  for (int j = 0; j < 8; ++j) acc[j] += __shfl_xor(acc[j], 32, 64);
  if (half == 0) {
    if (WRITE_I8) {
      float mx = 0.f;
#pragma unroll
      for (int j = 0; j < 8; ++j) mx = fmaxf(mx, fabsf(acc[j]));
#pragma unroll
      for (int off = 1; off < 32; off <<= 1)
        mx = fmaxf(mx, __shfl_xor(mx, off, 64));
      float inv = mx > 0.f ? 127.0f / mx : 0.f;
      uint w0 = 0, w1 = 0;
#pragma unroll
      for (int j = 0; j < 4; ++j)
        w0 |= ((uint)((int)rintf(acc[j] * inv) & 0xff)) << (8 * j);
#pragma unroll
      for (int j = 0; j < 4; ++j)
        w1 |= ((uint)((int)rintf(acc[4 + j] * inv) & 0xff)) << (8 * j);
      *reinterpret_cast<uint2*>(dst_i8 + (size_t)row * 256 + hl * 8) =
          make_uint2(w0, w1);
      if (hl == 0) dst_sc[row] = mx * (1.0f / 127.0f);
    } else {
      uint4 r;
      r.x = pack_bf16(acc[0], acc[1]);
      r.y = pack_bf16(acc[2], acc[3]);
      r.z = pack_bf16(acc[4], acc[5]);
      r.w = pack_bf16(acc[6], acc[7]);
      *reinterpret_cast<uint4*>(dst_bf + (size_t)row * 128 + hl * 4) = r;
    }
  }
}

__device__ __forceinline__ short8 dequant8(uint2 q, float sc) {
  float f0 = (float)((int)(q.x << 24) >> 24) * sc;
  float f1 = (float)((int)(q.x << 16) >> 24) * sc;
  float f2 = (float)((int)(q.x <<  8) >> 24) * sc;
  float f3 = (float)((int)q.x >> 24) * sc;
  float f4 = (float)((int)(q.y << 24) >> 24) * sc;
  float f5 = (float)((int)(q.y << 16) >> 24) * sc;
  float f6 = (float)((int)(q.y <<  8) >> 24) * sc;
  float f7 = (float)((int)q.y >> 24) * sc;
  uint4 v = make_uint4(pack_bf16(f0, f1), pack_bf16(f2, f3),
                       pack_bf16(f4, f5), pack_bf16(f6, f7));
  return __builtin_bit_cast(short8, v);
}

// out = relu(bias + x@Wt0 + S1@Wt1 + S2@Wt2 + S3@Wt3), MFMA 16x16x32 bf16.
// x,S3 bf16; S1,S2 int8 + per-node scale (dequantized in-register to A-frags).
__global__ __launch_bounds__(256) void gemm4_mfma(
    const uint* __restrict__ A0bf,
    const uchar* __restrict__ A1i8, const float* __restrict__ A1sc,
    const uchar* __restrict__ A2i8, const float* __restrict__ A2sc,
    const uint* __restrict__ A3bf,
    const uint* __restrict__ wtT,   // [64][128] words (bf16 [64][256])
    const float* __restrict__ bias, float* __restrict__ out) {
  __shared__ uint WS[64 * 132];
  __shared__ float bias_s[64];
  for (int w = threadIdx.x; w < 8192; w += 256)
    WS[(w >> 7) * 132 + (w & 127)] = wtT[w];
  if (threadIdx.x < 64) bias_s[threadIdx.x] = bias[threadIdx.x];
  __syncthreads();

  const int lane = threadIdx.x & 63;
  const int wv = threadIdx.x >> 6;
  const int r0 = blockIdx.x * 64 + wv * 16;
  const int c16 = lane & 15;
  const int hi = lane >> 4;

  const int ar = r0 + c16;                         // A row for this lane
  const size_t arow_w = (size_t)ar * 32 + hi * 4;  // bf16 word offset
  const size_t arow_b = (size_t)ar * 64 + hi * 8;  // i8 byte offset
  const float sc1 = A1sc[ar >> 2];
  const float sc2 = A2sc[ar >> 2];

  f32x4 acc[4] = {{0.f, 0.f, 0.f, 0.f}, {0.f, 0.f, 0.f, 0.f},
                  {0.f, 0.f, 0.f, 0.f}, {0.f, 0.f, 0.f, 0.f}};

#pragma unroll
  for (int ks = 0; ks < 8; ++ks) {
    short8 afrag;
    const int m = ks >> 1;
    if (m == 0) {
      uint4 av = *reinterpret_cast<const uint4*>(A0bf + arow_w + (ks & 1) * 16);
      afrag = __builtin_bit_cast(short8, av);
    } else if (m == 1) {
      uint2 qv = *reinterpret_cast<const uint2*>(A1i8 + arow_b + (ks & 1) * 32);
      afrag = dequant8(qv, sc1);
    } else if (m == 2) {
      uint2 qv = *reinterpret_cast<const uint2*>(A2i8 + arow_b + (ks & 1) * 32);
      afrag = dequant8(qv, sc2);
    } else {
      uint4 av = *reinterpret_cast<const uint4*>(A3bf + arow_w + (ks & 1) * 16);
      afrag = __builtin_bit_cast(short8, av);
    }
#pragma unroll
    for (int nt = 0; nt < 4; ++nt) {
      uint4 bv = *reinterpret_cast<const uint4*>(
          &WS[(nt * 16 + c16) * 132 + ks * 16 + hi * 4]);
      short8 bfrag = __builtin_bit_cast(short8, bv);
      acc[nt] = __builtin_amdgcn_mfma_f32_16x16x32_bf16(afrag, bfrag, acc[nt], 0, 0, 0);
    }
  }

  // C/D layout: col = lane&15, row = (lane>>4)*4 + i  [verified m89/m91]
#pragma unroll
  for (int nt = 0; nt < 4; ++nt) {
#pragma unroll
    for (int i = 0; i < 4; ++i) {
      int row = r0 + hi * 4 + i;
      int node = row >> 2, b = row & 3;
      int col = nt * 16 + c16;
      float v = acc[nt][i] + bias_s[col];
      out[(size_t)b * BN + (size_t)node * 64 + col] = fmaxf(v, 0.f);
    }
  }
}

extern "C" void kernel_launch(void* const* d_in, const int* in_sizes, int n_in,
                              void* d_out, int out_size, void* d_ws, size_t ws_size,
                              hipStream_t stream) {
  const float* x        = (const float*)d_in[0];
  const int*   lap_rows = (const int*)d_in[1];
  const int*   lap_cols = (const int*)d_in[2];
  const float* lap_vals = (const float*)d_in[3];
  const float* weights  = (const float*)d_in[4];  // [4][64][64]
  const float* bias     = (const float*)d_in[5];
  float* out = (float*)d_out;

  char* ws = (char*)d_ws;
  size_t off = 0;
  auto alloc = [&](size_t bytes) {
    void* p = ws + off;
    off += (bytes + 255) & ~(size_t)255;
    return p;
  };
  int*    gcounts     = (int*)alloc((size_t)NB * 4);
  int*    gcursor     = (int*)alloc((size_t)NB * 4);
  int*    bucket_base = (int*)alloc((size_t)(NB + 1) * 4);
  int*    row_start   = (int*)alloc((size_t)(N_NODES + 1) * 4);
  uint2*  pairs       = (uint2*)alloc((size_t)N_EDGES * 8);
  ushort* wtT         = (ushort*)alloc((size_t)64 * 256 * 2);
  uint*   xb          = (uint*)alloc((size_t)N_NODES * 128 * 4);   // bf16 25.6MB
  uchar*  S1i         = (uchar*)alloc((size_t)N_NODES * 256);      // i8 12.8MB
  uchar*  S2i         = (uchar*)alloc((size_t)N_NODES * 256);
  float*  S1sc        = (float*)alloc((size_t)N_NODES * 4);
  float*  S2sc        = (float*)alloc((size_t)N_NODES * 4);
  uint*   S3b         = (uint*)alloc((size_t)N_NODES * 128 * 4);   // bf16 25.6MB
  uint2*  staging     = (uint2*)S3b;  // alias: consumed before S3 is written
  (void)ws_size; (void)in_sizes; (void)n_in; (void)out_size;

  // Weight prep + x->bf16 interleave + CSR build (counting sort)
  wprep_kernel<<<64, 256, 0, stream>>>(weights, wtT);
  cvt_interleave_kernel<<<(BATCH * BN / 8 + 255) / 256, 256, 0, stream>>>(x, xb);
  hipMemsetAsync(gcounts, 0, (size_t)NB * 4, stream);
  bucket_hist<<<SCT_BLOCKS, 256, 0, stream>>>(lap_rows, gcounts);
  bucket_scan<<<1, 1024, 0, stream>>>(gcounts, bucket_base, gcursor);
  bucket_scatter<<<SCT_BLOCKS, 256, 0, stream>>>(lap_rows, lap_cols, lap_vals,
                                                 gcursor, staging);
  bucket_finalize<<<NB, 256, 0, stream>>>(bucket_base, staging, pairs, row_start);

  const int spmm_blocks = N_NODES / 4;  // 12500, one wave per node row

  // S1 = L x (bf16 gather -> i8) ; S2 = L S1 (i8 -> i8) ; S3 = L S2 (i8 -> bf16)
  spmm_kernel<0, 1><<<spmm_blocks, 256, 0, stream>>>(
      row_start, pairs, xb, nullptr, nullptr, nullptr, S1i, S1sc);
  spmm_kernel<1, 1><<<spmm_blocks, 256, 0, stream>>>(
      row_start, pairs, nullptr, S1i, S1sc, nullptr, S2i, S2sc);
  spmm_kernel<1, 0><<<spmm_blocks, 256, 0, stream>>>(
      row_start, pairs, nullptr, S2i, S2sc, S3b, nullptr, nullptr);
  // out = relu(bias + x@Wt0 + S1@Wt1 + S2@Wt2 + S3@Wt3)
  gemm4_mfma<<<ROWS_TOTAL / 64, 256, 0, stream>>>(xb, S1i, S1sc, S2i, S2sc, S3b,
                                                  (const uint*)wtT, bias, out);
}

// Round 9
// 210.811 us; speedup vs baseline: 5.5201x; 1.0803x over previous
//
#include <hip/hip_runtime.h>

// ChebyshevGCNN: out = relu(bias + x@W0 + T1@W1 + T2@W2 + T3@W3)
// Reassociated: S1=Lx, S2=LS1, S3=LS2;  T2=2S2-x, T3=4S3-3S1
//   => out = relu(bias + x@(W0-W2) + S1@(W1-3W3) + S2@(2W2) + S3@(4W3))
// Round 9: all spmm passes int8->int8 (x quantized per node too); 4 edges per
// wave-instruction (16 lanes x 16B per edge) to halve gather-instruction count;
// S3 also i8 (gemm dequantizes); distinct kernel names per pass for profiling.

#define N_NODES 50000
#define N_EDGES 800000
#define BATCH 4
#define CH 64
#define BN (N_NODES * CH)             // elems per batch matrix (out layout)
#define ROWS_TOTAL (BATCH * N_NODES)  // 200,000
#define NB 782                        // buckets of 64 rows: 782*64 = 50048
#define EPB 8192                      // edges per block in bucket passes
#define SCT_BLOCKS ((N_EDGES + EPB - 1) / EPB)  // 98

typedef unsigned int uint;
typedef unsigned short ushort;
typedef unsigned char uchar;
typedef __attribute__((ext_vector_type(8))) short short8;   // 8 x bf16
typedef __attribute__((ext_vector_type(4))) float f32x4;

__device__ __forceinline__ uint pack_bf16(float lo, float hi) {
  uint a = __float_as_uint(lo);
  uint b = __float_as_uint(hi);
  a = (a + 0x7fffu + ((a >> 16) & 1u)) >> 16;  // RN-even
  b = (b + 0x7fffu + ((b >> 16) & 1u)) >> 16;
  return a | (b << 16);
}
__device__ __forceinline__ ushort bf16one(float x) {
  uint a = __float_as_uint(x);
  a = (a + 0x7fffu + ((a >> 16) & 1u)) >> 16;
  return (ushort)a;
}

// ---------------- CSR build: two-level counting sort ----------------
__global__ __launch_bounds__(256) void bucket_hist(const int* __restrict__ rows,
                                                   int* __restrict__ gcounts) {
  __shared__ int h[NB];
  for (int b = threadIdx.x; b < NB; b += 256) h[b] = 0;
  __syncthreads();
  int base_e = blockIdx.x * EPB;
#pragma unroll
  for (int j = 0; j < EPB / 256; ++j) {
    int e = base_e + j * 256 + threadIdx.x;
    if (e < N_EDGES) atomicAdd(&h[rows[e] >> 6], 1);
  }
  __syncthreads();
  for (int b = threadIdx.x; b < NB; b += 256)
    if (h[b]) atomicAdd(&gcounts[b], h[b]);
}

__global__ __launch_bounds__(1024) void bucket_scan(const int* __restrict__ gcounts,
                                                    int* __restrict__ bucket_base,
                                                    int* __restrict__ gcursor) {
  __shared__ int s[1024];
  int t = threadIdx.x;
  int v = (t < NB) ? gcounts[t] : 0;
  s[t] = v;
  __syncthreads();
  for (int off = 1; off < 1024; off <<= 1) {
    int tv = (t >= off) ? s[t - off] : 0;
    __syncthreads();
    s[t] += tv;
    __syncthreads();
  }
  int ex = s[t] - v;
  if (t < NB) { bucket_base[t] = ex; gcursor[t] = ex; }
  if (t == NB) bucket_base[NB] = N_EDGES;
}

__global__ __launch_bounds__(256) void bucket_scatter(const int* __restrict__ rows,
                                                      const int* __restrict__ cols,
                                                      const float* __restrict__ vals,
                                                      int* __restrict__ gcursor,
                                                      uint2* __restrict__ staging) {
  __shared__ int lcur[NB];
  for (int b = threadIdx.x; b < NB; b += 256) lcur[b] = 0;
  __syncthreads();
  int base_e = blockIdx.x * EPB;
#pragma unroll
  for (int j = 0; j < EPB / 256; ++j) {
    int e = base_e + j * 256 + threadIdx.x;
    if (e < N_EDGES) atomicAdd(&lcur[rows[e] >> 6], 1);
  }
  __syncthreads();
  for (int b = threadIdx.x; b < NB; b += 256) {
    int c = lcur[b];
    lcur[b] = (c > 0) ? atomicAdd(&gcursor[b], c) : 0;
  }
  __syncthreads();
#pragma unroll
  for (int j = 0; j < EPB / 256; ++j) {
    int e = base_e + j * 256 + threadIdx.x;
    if (e < N_EDGES) {
      int r = rows[e];
      int pos = atomicAdd(&lcur[r >> 6], 1);
      staging[pos] = make_uint2((uint)cols[e] | ((uint)(r & 63) << 20),
                                __float_as_uint(vals[e]));
    }
  }
}

__global__ __launch_bounds__(256) void bucket_finalize(const int* __restrict__ bucket_base,
                                                       const uint2* __restrict__ staging,
                                                       uint2* __restrict__ pairs,
                                                       int* __restrict__ row_start) {
  int b = blockIdx.x;
  int seg0 = bucket_base[b], seg1 = bucket_base[b + 1];
  __shared__ int hist[64];
  __shared__ int cur[64];
  if (threadIdx.x < 64) hist[threadIdx.x] = 0;
  __syncthreads();
  for (int i = seg0 + threadIdx.x; i < seg1; i += 256)
    atomicAdd(&hist[staging[i].x >> 20], 1);
  __syncthreads();
  if (threadIdx.x < 64) {
    int v = hist[threadIdx.x];
    int sc = v;
#pragma unroll
    for (int off = 1; off < 64; off <<= 1) {
      int t = __shfl_up(sc, off, 64);
      if (threadIdx.x >= (unsigned)off) sc += t;
    }
    int start = seg0 + sc - v;  // exclusive
    cur[threadIdx.x] = start;
    int r = b * 64 + threadIdx.x;
    if (r < N_NODES) row_start[r] = start;
    if (r == N_NODES) row_start[N_NODES] = N_EDGES;
  }
  __syncthreads();
  for (int i = seg0 + threadIdx.x; i < seg1; i += 256) {
    uint2 eu = staging[i];
    int rl = eu.x >> 20;
    int pos = atomicAdd(&cur[rl], 1);
    pairs[pos] = make_uint2(eu.x & 0xFFFFFu, eu.y);
  }
}

// Modified weights, transposed + bf16: wtT[o][k], k = m*64+c, m in 0..3.
__global__ __launch_bounds__(256) void wprep_kernel(const float* __restrict__ w,
                                                    ushort* __restrict__ wtT) {
  int t = blockIdx.x * 256 + threadIdx.x;
  if (t >= 64 * 256) return;
  int o = t >> 8, k = t & 255, m = k >> 6, c = k & 63;
  int idx = c * 64 + o;
  float v;
  if (m == 0)      v = w[idx] - w[2 * 4096 + idx];
  else if (m == 1) v = w[4096 + idx] - 3.0f * w[3 * 4096 + idx];
  else if (m == 2) v = 2.0f * w[2 * 4096 + idx];
  else             v = 4.0f * w[3 * 4096 + idx];
  wtT[t] = bf16one(v);
}

// One wave per node: f32 [b][node][64] -> bf16 interleaved [node][b][64]
// AND i8 [node][256] + per-node scale. lane: b=lane>>4, ch4=(lane&15)*4.
__global__ __launch_bounds__(256) void cvt_kernel(const float* __restrict__ in,
                                                  uint* __restrict__ xb,
                                                  uint* __restrict__ xi8w,
                                                  float* __restrict__ xsc) {
  int node = blockIdx.x * 4 + (threadIdx.x >> 6);
  int lane = threadIdx.x & 63;
  int b = lane >> 4;
  int ch4 = (lane & 15) * 4;
  float4 v = *reinterpret_cast<const float4*>(in + (size_t)b * BN + (size_t)node * 64 + ch4);
  // bf16 interleaved write (2 words = 4 vals)
  uint2 bw = make_uint2(pack_bf16(v.x, v.y), pack_bf16(v.z, v.w));
  *reinterpret_cast<uint2*>(xb + (size_t)node * 128 + b * 32 + (lane & 15) * 2) = bw;
  // per-node max over 256 vals
  float mx = fmaxf(fmaxf(fabsf(v.x), fabsf(v.y)), fmaxf(fabsf(v.z), fabsf(v.w)));
#pragma unroll
  for (int off = 1; off < 64; off <<= 1) mx = fmaxf(mx, __shfl_xor(mx, off, 64));
  float inv = mx > 0.f ? 127.0f / mx : 0.f;
  uint w8 = ((uint)((int)rintf(v.x * inv) & 0xff)) |
            ((uint)((int)rintf(v.y * inv) & 0xff) << 8) |
            ((uint)((int)rintf(v.z * inv) & 0xff) << 16) |
            ((uint)((int)rintf(v.w * inv) & 0xff) << 24);
  xi8w[(size_t)node * 64 + lane] = w8;
  if (lane == 0) xsc[node] = mx * (1.0f / 127.0f);
}

__device__ __forceinline__ void fma16(float acc[16], float m, const uint4& w) {
  const uint arr[4] = {w.x, w.y, w.z, w.w};
#pragma unroll
  for (int t = 0; t < 4; ++t) {
    uint u = arr[t];
    acc[t * 4 + 0] = fmaf(m, (float)((int)(u << 24) >> 24), acc[t * 4 + 0]);
    acc[t * 4 + 1] = fmaf(m, (float)((int)(u << 16) >> 24), acc[t * 4 + 1]);
    acc[t * 4 + 2] = fmaf(m, (float)((int)(u <<  8) >> 24), acc[t * 4 + 2]);
    acc[t * 4 + 3] = fmaf(m, (float)((int)u >> 24),         acc[t * 4 + 3]);
  }
}

// dst = L * src, i8 in / i8 out, per-node scales. One wave per dest node.
// lane = (quarter q, ql): 16 lanes x 16B = one 256B edge block, 4 edges per
// VMEM instruction, 2-deep unroll (8 edges in flight). Butterfly fold q.
__device__ __forceinline__ void spmm_body(const int* __restrict__ row_start,
                                          const uint2* __restrict__ pairs,
                                          const uchar* __restrict__ src,
                                          const float* __restrict__ ssc,
                                          uchar* __restrict__ dst,
                                          float* __restrict__ dsc) {
  int row = blockIdx.x * 4 + (threadIdx.x >> 6);
  int lane = threadIdx.x & 63;
  int q = lane >> 4;
  int ql = lane & 15;
  const uchar* sb = src + ql * 16;
  int s = row_start[row], e = row_start[row + 1];
  float acc[16];
#pragma unroll
  for (int j = 0; j < 16; ++j) acc[j] = 0.f;
  int i = s;
  for (; i + 7 < e; i += 8) {
    uint2 pa = pairs[i + q];
    uint2 pb = pairs[i + 4 + q];
    uint4 qa = *reinterpret_cast<const uint4*>(sb + (size_t)pa.x * 256);
    uint4 qb = *reinterpret_cast<const uint4*>(sb + (size_t)pb.x * 256);
    float ma = __uint_as_float(pa.y) * ssc[pa.x];
    float mb = __uint_as_float(pb.y) * ssc[pb.x];
    fma16(acc, ma, qa);
    fma16(acc, mb, qb);
  }
  for (; i < e; i += 4) {
    if (i + q < e) {
      uint2 p0 = pairs[i + q];
      uint4 q0 = *reinterpret_cast<const uint4*>(sb + (size_t)p0.x * 256);
      fma16(acc, __uint_as_float(p0.y) * ssc[p0.x], q0);
    }
  }
  // fold across quarters (lanes differing in bits 4,5)
#pragma unroll
  for (int j = 0; j < 16; ++j) {
    acc[j] += __shfl_xor(acc[j], 16, 64);
    acc[j] += __shfl_xor(acc[j], 32, 64);
  }
  // per-node max (lanes within a quarter hold disjoint slices; quarters equal)
  float mx = 0.f;
#pragma unroll
  for (int j = 0; j < 16; ++j) mx = fmaxf(mx, fabsf(acc[j]));
#pragma unroll
  for (int off = 1; off < 16; off <<= 1) mx = fmaxf(mx, __shfl_xor(mx, off, 64));
  if (lane < 16) {
    float inv = mx > 0.f ? 127.0f / mx : 0.f;
    uint w[4];
#pragma unroll
    for (int t = 0; t < 4; ++t) {
      w[t] = ((uint)((int)rintf(acc[t * 4 + 0] * inv) & 0xff)) |
             ((uint)((int)rintf(acc[t * 4 + 1] * inv) & 0xff) << 8) |
             ((uint)((int)rintf(acc[t * 4 + 2] * inv) & 0xff) << 16) |
             ((uint)((int)rintf(acc[t * 4 + 3] * inv) & 0xff) << 24);
    }
    *reinterpret_cast<uint4*>(dst + (size_t)row * 256 + ql * 16) =
        make_uint4(w[0], w[1], w[2], w[3]);
    if (lane == 0) dsc[row] = mx * (1.0f / 127.0f);
  }
}

__global__ __launch_bounds__(256) void spmm_s1(const int* __restrict__ rs,
                                               const uint2* __restrict__ pr,
                                               const uchar* __restrict__ src,
                                               const float* __restrict__ ssc,
                                               uchar* __restrict__ dst,
                                               float* __restrict__ dsc) {
  spmm_body(rs, pr, src, ssc, dst, dsc);
}
__global__ __launch_bounds__(256) void spmm_s2(const int* __restrict__ rs,
                                               const uint2* __restrict__ pr,
                                               const uchar* __restrict__ src,
                                               const float* __restrict__ ssc,
                                               uchar* __restrict__ dst,
                                               float* __restrict__ dsc) {
  spmm_body(rs, pr, src, ssc, dst, dsc);
}
__global__ __launch_bounds__(256) void spmm_s3(const int* __restrict__ rs,
                                               const uint2* __restrict__ pr,
                                               const uchar* __restrict__ src,
                                               const float* __restrict__ ssc,
                                               uchar* __restrict__ dst,
                                               float* __restrict__ dsc) {
  spmm_body(rs, pr, src, ssc, dst, dsc);
}

__device__ __forceinline__ short8 dequant8(uint2 q, float sc) {
  float f0 = (float)((int)(q.x << 24) >> 24) * sc;
  float f1 = (float)((int)(q.x << 16) >> 24) * sc;
  float f2 = (float)((int)(q.x <<  8) >> 24) * sc;
  float f3 = (float)((int)q.x >> 24) * sc;
  float f4 = (float)((int)(q.y << 24) >> 24) * sc;
  float f5 = (float)((int)(q.y << 16) >> 24) * sc;
  float f6 = (float)((int)(q.y <<  8) >> 24) * sc;
  float f7 = (float)((int)q.y >> 24) * sc;
  uint4 v = make_uint4(pack_bf16(f0, f1), pack_bf16(f2, f3),
                       pack_bf16(f4, f5), pack_bf16(f6, f7));
  return __builtin_bit_cast(short8, v);
}

// out = relu(bias + x@Wt0 + S1@Wt1 + S2@Wt2 + S3@Wt3), MFMA 16x16x32 bf16.
// x bf16; S1,S2,S3 int8 + per-node scale (dequantized in-register to A-frags).
__global__ __launch_bounds__(256) void gemm4_mfma(
    const uint* __restrict__ A0bf,
    const uchar* __restrict__ A1i8, const float* __restrict__ A1sc,
    const uchar* __restrict__ A2i8, const float* __restrict__ A2sc,
    const uchar* __restrict__ A3i8, const float* __restrict__ A3sc,
    const uint* __restrict__ wtT,   // [64][128] words (bf16 [64][256])
    const float* __restrict__ bias, float* __restrict__ out) {
  __shared__ uint WS[64 * 132];
  __shared__ float bias_s[64];
  for (int w = threadIdx.x; w < 8192; w += 256)
    WS[(w >> 7) * 132 + (w & 127)] = wtT[w];
  if (threadIdx.x < 64) bias_s[threadIdx.x] = bias[threadIdx.x];
  __syncthreads();

  const int lane = threadIdx.x & 63;
  const int wv = threadIdx.x >> 6;
  const int r0 = blockIdx.x * 64 + wv * 16;
  const int c16 = lane & 15;
  const int hi = lane >> 4;

  const int ar = r0 + c16;                         // A row for this lane
  const size_t arow_w = (size_t)ar * 32 + hi * 4;  // bf16 word offset
  const size_t arow_b = (size_t)ar * 64 + hi * 8;  // i8 byte offset
  const int nd = ar >> 2;
  const float sc1 = A1sc[nd];
  const float sc2 = A2sc[nd];
  const float sc3 = A3sc[nd];

  f32x4 acc[4] = {{0.f, 0.f, 0.f, 0.f}, {0.f, 0.f, 0.f, 0.f},
                  {0.f, 0.f, 0.f, 0.f}, {0.f, 0.f, 0.f, 0.f}};

#pragma unroll
  for (int ks = 0; ks < 8; ++ks) {
    short8 afrag;
    const int m = ks >> 1;
    if (m == 0) {
      uint4 av = *reinterpret_cast<const uint4*>(A0bf + arow_w + (ks & 1) * 16);
      afrag = __builtin_bit_cast(short8, av);
    } else if (m == 1) {
      uint2 qv = *reinterpret_cast<const uint2*>(A1i8 + arow_b + (ks & 1) * 32);
      afrag = dequant8(qv, sc1);
    } else if (m == 2) {
      uint2 qv = *reinterpret_cast<const uint2*>(A2i8 + arow_b + (ks & 1) * 32);
      afrag = dequant8(qv, sc2);
    } else {
      uint2 qv = *reinterpret_cast<const uint2*>(A3i8 + arow_b + (ks & 1) * 32);
      afrag = dequant8(qv, sc3);
    }
#pragma unroll
    for (int nt = 0; nt < 4; ++nt) {
      uint4 bv = *reinterpret_cast<const uint4*>(
          &WS[(nt * 16 + c16) * 132 + ks * 16 + hi * 4]);
      short8 bfrag = __builtin_bit_cast(short8, bv);
      acc[nt] = __builtin_amdgcn_mfma_f32_16x16x32_bf16(afrag, bfrag, acc[nt], 0, 0, 0);
    }
  }

  // C/D layout: col = lane&15, row = (lane>>4)*4 + i  [verified m89/m91]
#pragma unroll
  for (int nt = 0; nt < 4; ++nt) {
#pragma unroll
    for (int i = 0; i < 4; ++i) {
      int row = r0 + hi * 4 + i;
      int node = row >> 2, b = row & 3;
      int col = nt * 16 + c16;
      float v = acc[nt][i] + bias_s[col];
      out[(size_t)b * BN + (size_t)node * 64 + col] = fmaxf(v, 0.f);
    }
  }
}

extern "C" void kernel_launch(void* const* d_in, const int* in_sizes, int n_in,
                              void* d_out, int out_size, void* d_ws, size_t ws_size,
                              hipStream_t stream) {
  const float* x        = (const float*)d_in[0];
  const int*   lap_rows = (const int*)d_in[1];
  const int*   lap_cols = (const int*)d_in[2];
  const float* lap_vals = (const float*)d_in[3];
  const float* weights  = (const float*)d_in[4];  // [4][64][64]
  const float* bias     = (const float*)d_in[5];
  float* out = (float*)d_out;

  char* ws = (char*)d_ws;
  size_t off = 0;
  auto alloc = [&](size_t bytes) {
    void* p = ws + off;
    off += (bytes + 255) & ~(size_t)255;
    return p;
  };
  int*    gcounts     = (int*)alloc((size_t)NB * 4);
  int*    gcursor     = (int*)alloc((size_t)NB * 4);
  int*    bucket_base = (int*)alloc((size_t)(NB + 1) * 4);
  int*    row_start   = (int*)alloc((size_t)(N_NODES + 1) * 4);
  uint2*  pairs       = (uint2*)alloc((size_t)N_EDGES * 8);
  uint2*  staging     = (uint2*)alloc((size_t)N_EDGES * 8);
  ushort* wtT         = (ushort*)alloc((size_t)64 * 256 * 2);
  uint*   xb          = (uint*)alloc((size_t)N_NODES * 128 * 4);  // bf16 25.6MB
  uchar*  xi8         = (uchar*)alloc((size_t)N_NODES * 256);     // 12.8MB each
  uchar*  S1i         = (uchar*)alloc((size_t)N_NODES * 256);
  uchar*  S2i         = (uchar*)alloc((size_t)N_NODES * 256);
  uchar*  S3i         = (uchar*)alloc((size_t)N_NODES * 256);
  float*  xsc         = (float*)alloc((size_t)N_NODES * 4);
  float*  S1sc        = (float*)alloc((size_t)N_NODES * 4);
  float*  S2sc        = (float*)alloc((size_t)N_NODES * 4);
  float*  S3sc        = (float*)alloc((size_t)N_NODES * 4);
  (void)ws_size; (void)in_sizes; (void)n_in; (void)out_size;

  // Weight prep + x conversion + CSR build (counting sort)
  wprep_kernel<<<64, 256, 0, stream>>>(weights, wtT);
  cvt_kernel<<<N_NODES / 4, 256, 0, stream>>>(x, xb, (uint*)xi8, xsc);
  hipMemsetAsync(gcounts, 0, (size_t)NB * 4, stream);
  bucket_hist<<<SCT_BLOCKS, 256, 0, stream>>>(lap_rows, gcounts);
  bucket_scan<<<1, 1024, 0, stream>>>(gcounts, bucket_base, gcursor);
  bucket_scatter<<<SCT_BLOCKS, 256, 0, stream>>>(lap_rows, lap_cols, lap_vals,
                                                 gcursor, staging);
  bucket_finalize<<<NB, 256, 0, stream>>>(bucket_base, staging, pairs, row_start);

  const int spmm_blocks = N_NODES / 4;  // 12500, one wave per node row

  // S1 = L x ; S2 = L S1 ; S3 = L S2  (all i8 -> i8, per-node scales)
  spmm_s1<<<spmm_blocks, 256, 0, stream>>>(row_start, pairs, xi8, xsc, S1i, S1sc);
  spmm_s2<<<spmm_blocks, 256, 0, stream>>>(row_start, pairs, S1i, S1sc, S2i, S2sc);
  spmm_s3<<<spmm_blocks, 256, 0, stream>>>(row_start, pairs, S2i, S2sc, S3i, S3sc);
  // out = relu(bias + x@Wt0 + S1@Wt1 + S2@Wt2 + S3@Wt3)
  gemm4_mfma<<<ROWS_TOTAL / 64, 256, 0, stream>>>(xb, S1i, S1sc, S2i, S2sc,
                                                  S3i, S3sc, (const uint*)wtT,
                                                  bias, out);
}

// Round 10
// 191.672 us; speedup vs baseline: 6.0713x; 1.0999x over previous
//
#include <hip/hip_runtime.h>

// ChebyshevGCNN: out = relu(bias + x@W0 + T1@W1 + T2@W2 + T3@W3)
// Reassociated: S1=Lx, S2=LS1, S3=LS2;  T2=2S2-x, T3=4S3-3S1
//   => out = relu(bias + x@(W0-W2) + S1@(W1-3W3) + S2@(2W2) + S3@(4W3))
// Round 10: bucket_hist/bucket_scatter at 1024 threads/block (4x waves, 4x
// fewer serial iterations) — fixes the 3.3%-occupancy 44us scatter.
// EPB stays 8192 to preserve staging write locality.

#define N_NODES 50000
#define N_EDGES 800000
#define BATCH 4
#define CH 64
#define BN (N_NODES * CH)             // elems per batch matrix (out layout)
#define ROWS_TOTAL (BATCH * N_NODES)  // 200,000
#define NB 782                        // buckets of 64 rows: 782*64 = 50048
#define EPB 8192                      // edges per block in bucket passes
#define SCT_BLOCKS ((N_EDGES + EPB - 1) / EPB)  // 98

typedef unsigned int uint;
typedef unsigned short ushort;
typedef unsigned char uchar;
typedef __attribute__((ext_vector_type(8))) short short8;   // 8 x bf16
typedef __attribute__((ext_vector_type(4))) float f32x4;

__device__ __forceinline__ uint pack_bf16(float lo, float hi) {
  uint a = __float_as_uint(lo);
  uint b = __float_as_uint(hi);
  a = (a + 0x7fffu + ((a >> 16) & 1u)) >> 16;  // RN-even
  b = (b + 0x7fffu + ((b >> 16) & 1u)) >> 16;
  return a | (b << 16);
}
__device__ __forceinline__ ushort bf16one(float x) {
  uint a = __float_as_uint(x);
  a = (a + 0x7fffu + ((a >> 16) & 1u)) >> 16;
  return (ushort)a;
}

// ---------------- CSR build: two-level counting sort ----------------
// 1024 threads: 8 edges per thread, 16 waves to hide LDS-atomic latency.
__global__ __launch_bounds__(1024) void bucket_hist(const int* __restrict__ rows,
                                                    int* __restrict__ gcounts) {
  __shared__ int h[NB];
  for (int b = threadIdx.x; b < NB; b += 1024) h[b] = 0;
  __syncthreads();
  int base_e = blockIdx.x * EPB;
#pragma unroll
  for (int j = 0; j < EPB / 1024; ++j) {
    int e = base_e + j * 1024 + threadIdx.x;
    if (e < N_EDGES) atomicAdd(&h[rows[e] >> 6], 1);
  }
  __syncthreads();
  for (int b = threadIdx.x; b < NB; b += 1024)
    if (h[b]) atomicAdd(&gcounts[b], h[b]);
}

__global__ __launch_bounds__(1024) void bucket_scan(const int* __restrict__ gcounts,
                                                    int* __restrict__ bucket_base,
                                                    int* __restrict__ gcursor) {
  __shared__ int s[1024];
  int t = threadIdx.x;
  int v = (t < NB) ? gcounts[t] : 0;
  s[t] = v;
  __syncthreads();
  for (int off = 1; off < 1024; off <<= 1) {
    int tv = (t >= off) ? s[t - off] : 0;
    __syncthreads();
    s[t] += tv;
    __syncthreads();
  }
  int ex = s[t] - v;
  if (t < NB) { bucket_base[t] = ex; gcursor[t] = ex; }
  if (t == NB) bucket_base[NB] = N_EDGES;
}

__global__ __launch_bounds__(1024) void bucket_scatter(const int* __restrict__ rows,
                                                       const int* __restrict__ cols,
                                                       const float* __restrict__ vals,
                                                       int* __restrict__ gcursor,
                                                       uint2* __restrict__ staging) {
  __shared__ int lcur[NB];
  for (int b = threadIdx.x; b < NB; b += 1024) lcur[b] = 0;
  __syncthreads();
  int base_e = blockIdx.x * EPB;
#pragma unroll
  for (int j = 0; j < EPB / 1024; ++j) {
    int e = base_e + j * 1024 + threadIdx.x;
    if (e < N_EDGES) atomicAdd(&lcur[rows[e] >> 6], 1);
  }
  __syncthreads();
  for (int b = threadIdx.x; b < NB; b += 1024) {
    int c = lcur[b];
    lcur[b] = (c > 0) ? atomicAdd(&gcursor[b], c) : 0;
  }
  __syncthreads();
#pragma unroll
  for (int j = 0; j < EPB / 1024; ++j) {
    int e = base_e + j * 1024 + threadIdx.x;
    if (e < N_EDGES) {
      int r = rows[e];
      int pos = atomicAdd(&lcur[r >> 6], 1);
      staging[pos] = make_uint2((uint)cols[e] | ((uint)(r & 63) << 20),
                                __float_as_uint(vals[e]));
    }
  }
}

__global__ __launch_bounds__(256) void bucket_finalize(const int* __restrict__ bucket_base,
                                                       const uint2* __restrict__ staging,
                                                       uint2* __restrict__ pairs,
                                                       int* __restrict__ row_start) {
  int b = blockIdx.x;
  int seg0 = bucket_base[b], seg1 = bucket_base[b + 1];
  __shared__ int hist[64];
  __shared__ int cur[64];
  if (threadIdx.x < 64) hist[threadIdx.x] = 0;
  __syncthreads();
  for (int i = seg0 + threadIdx.x; i < seg1; i += 256)
    atomicAdd(&hist[staging[i].x >> 20], 1);
  __syncthreads();
  if (threadIdx.x < 64) {
    int v = hist[threadIdx.x];
    int sc = v;
#pragma unroll
    for (int off = 1; off < 64; off <<= 1) {
      int t = __shfl_up(sc, off, 64);
      if (threadIdx.x >= (unsigned)off) sc += t;
    }
    int start = seg0 + sc - v;  // exclusive
    cur[threadIdx.x] = start;
    int r = b * 64 + threadIdx.x;
    if (r < N_NODES) row_start[r] = start;
    if (r == N_NODES) row_start[N_NODES] = N_EDGES;
  }
  __syncthreads();
  for (int i = seg0 + threadIdx.x; i < seg1; i += 256) {
    uint2 eu = staging[i];
    int rl = eu.x >> 20;
    int pos = atomicAdd(&cur[rl], 1);
    pairs[pos] = make_uint2(eu.x & 0xFFFFFu, eu.y);
  }
}

// Modified weights, transposed + bf16: wtT[o][k], k = m*64+c, m in 0..3.
__global__ __launch_bounds__(256) void wprep_kernel(const float* __restrict__ w,
                                                    ushort* __restrict__ wtT) {
  int t = blockIdx.x * 256 + threadIdx.x;
  if (t >= 64 * 256) return;
  int o = t >> 8, k = t & 255, m = k >> 6, c = k & 63;
  int idx = c * 64 + o;
  float v;
  if (m == 0)      v = w[idx] - w[2 * 4096 + idx];
  else if (m == 1) v = w[4096 + idx] - 3.0f * w[3 * 4096 + idx];
  else if (m == 2) v = 2.0f * w[2 * 4096 + idx];
  else             v = 4.0f * w[3 * 4096 + idx];
  wtT[t] = bf16one(v);
}

// One wave per node: f32 [b][node][64] -> bf16 interleaved [node][b][64]
// AND i8 [node][256] + per-node scale. lane: b=lane>>4, ch4=(lane&15)*4.
__global__ __launch_bounds__(256) void cvt_kernel(const float* __restrict__ in,
                                                  uint* __restrict__ xb,
                                                  uint* __restrict__ xi8w,
                                                  float* __restrict__ xsc) {
  int node = blockIdx.x * 4 + (threadIdx.x >> 6);
  int lane = threadIdx.x & 63;
  int b = lane >> 4;
  int ch4 = (lane & 15) * 4;
  float4 v = *reinterpret_cast<const float4*>(in + (size_t)b * BN + (size_t)node * 64 + ch4);
  // bf16 interleaved write (2 words = 4 vals)
  uint2 bw = make_uint2(pack_bf16(v.x, v.y), pack_bf16(v.z, v.w));
  *reinterpret_cast<uint2*>(xb + (size_t)node * 128 + b * 32 + (lane & 15) * 2) = bw;
  // per-node max over 256 vals
  float mx = fmaxf(fmaxf(fabsf(v.x), fabsf(v.y)), fmaxf(fabsf(v.z), fabsf(v.w)));
#pragma unroll
  for (int off = 1; off < 64; off <<= 1) mx = fmaxf(mx, __shfl_xor(mx, off, 64));
  float inv = mx > 0.f ? 127.0f / mx : 0.f;
  uint w8 = ((uint)((int)rintf(v.x * inv) & 0xff)) |
            ((uint)((int)rintf(v.y * inv) & 0xff) << 8) |
            ((uint)((int)rintf(v.z * inv) & 0xff) << 16) |
            ((uint)((int)rintf(v.w * inv) & 0xff) << 24);
  xi8w[(size_t)node * 64 + lane] = w8;
  if (lane == 0) xsc[node] = mx * (1.0f / 127.0f);
}

__device__ __forceinline__ void fma16(float acc[16], float m, const uint4& w) {
  const uint arr[4] = {w.x, w.y, w.z, w.w};
#pragma unroll
  for (int t = 0; t < 4; ++t) {
    uint u = arr[t];
    acc[t * 4 + 0] = fmaf(m, (float)((int)(u << 24) >> 24), acc[t * 4 + 0]);
    acc[t * 4 + 1] = fmaf(m, (float)((int)(u << 16) >> 24), acc[t * 4 + 1]);
    acc[t * 4 + 2] = fmaf(m, (float)((int)(u <<  8) >> 24), acc[t * 4 + 2]);
    acc[t * 4 + 3] = fmaf(m, (float)((int)u >> 24),         acc[t * 4 + 3]);
  }
}

// dst = L * src, i8 in / i8 out, per-node scales. One wave per dest node.
// lane = (quarter q, ql): 16 lanes x 16B = one 256B edge block, 4 edges per
// VMEM instruction, 2-deep unroll (8 edges in flight). Butterfly fold q.
__device__ __forceinline__ void spmm_body(const int* __restrict__ row_start,
                                          const uint2* __restrict__ pairs,
                                          const uchar* __restrict__ src,
                                          const float* __restrict__ ssc,
                                          uchar* __restrict__ dst,
                                          float* __restrict__ dsc) {
  int row = blockIdx.x * 4 + (threadIdx.x >> 6);
  int lane = threadIdx.x & 63;
  int q = lane >> 4;
  int ql = lane & 15;
  const uchar* sb = src + ql * 16;
  int s = row_start[row], e = row_start[row + 1];
  float acc[16];
#pragma unroll
  for (int j = 0; j < 16; ++j) acc[j] = 0.f;
  int i = s;
  for (; i + 7 < e; i += 8) {
    uint2 pa = pairs[i + q];
    uint2 pb = pairs[i + 4 + q];
    uint4 qa = *reinterpret_cast<const uint4*>(sb + (size_t)pa.x * 256);
    uint4 qb = *reinterpret_cast<const uint4*>(sb + (size_t)pb.x * 256);
    float ma = __uint_as_float(pa.y) * ssc[pa.x];
    float mb = __uint_as_float(pb.y) * ssc[pb.x];
    fma16(acc, ma, qa);
    fma16(acc, mb, qb);
  }
  for (; i < e; i += 4) {
    if (i + q < e) {
      uint2 p0 = pairs[i + q];
      uint4 q0 = *reinterpret_cast<const uint4*>(sb + (size_t)p0.x * 256);
      fma16(acc, __uint_as_float(p0.y) * ssc[p0.x], q0);
    }
  }
  // fold across quarters (lanes differing in bits 4,5)
#pragma unroll
  for (int j = 0; j < 16; ++j) {
    acc[j] += __shfl_xor(acc[j], 16, 64);
    acc[j] += __shfl_xor(acc[j], 32, 64);
  }
  // per-node max (lanes within a quarter hold disjoint slices; quarters equal)
  float mx = 0.f;
#pragma unroll
  for (int j = 0; j < 16; ++j) mx = fmaxf(mx, fabsf(acc[j]));
#pragma unroll
  for (int off = 1; off < 16; off <<= 1) mx = fmaxf(mx, __shfl_xor(mx, off, 64));
  if (lane < 16) {
    float inv = mx > 0.f ? 127.0f / mx : 0.f;
    uint w[4];
#pragma unroll
    for (int t = 0; t < 4; ++t) {
      w[t] = ((uint)((int)rintf(acc[t * 4 + 0] * inv) & 0xff)) |
             ((uint)((int)rintf(acc[t * 4 + 1] * inv) & 0xff) << 8) |
             ((uint)((int)rintf(acc[t * 4 + 2] * inv) & 0xff) << 16) |
             ((uint)((int)rintf(acc[t * 4 + 3] * inv) & 0xff) << 24);
    }
    *reinterpret_cast<uint4*>(dst + (size_t)row * 256 + ql * 16) =
        make_uint4(w[0], w[1], w[2], w[3]);
    if (lane == 0) dsc[row] = mx * (1.0f / 127.0f);
  }
}

__global__ __launch_bounds__(256) void spmm_s1(const int* __restrict__ rs,
                                               const uint2* __restrict__ pr,
                                               const uchar* __restrict__ src,
                                               const float* __restrict__ ssc,
                                               uchar* __restrict__ dst,
                                               float* __restrict__ dsc) {
  spmm_body(rs, pr, src, ssc, dst, dsc);
}
__global__ __launch_bounds__(256) void spmm_s2(const int* __restrict__ rs,
                                               const uint2* __restrict__ pr,
                                               const uchar* __restrict__ src,
                                               const float* __restrict__ ssc,
                                               uchar* __restrict__ dst,
                                               float* __restrict__ dsc) {
  spmm_body(rs, pr, src, ssc, dst, dsc);
}
__global__ __launch_bounds__(256) void spmm_s3(const int* __restrict__ rs,
                                               const uint2* __restrict__ pr,
                                               const uchar* __restrict__ src,
                                               const float* __restrict__ ssc,
                                               uchar* __restrict__ dst,
                                               float* __restrict__ dsc) {
  spmm_body(rs, pr, src, ssc, dst, dsc);
}

__device__ __forceinline__ short8 dequant8(uint2 q, float sc) {
  float f0 = (float)((int)(q.x << 24) >> 24) * sc;
  float f1 = (float)((int)(q.x << 16) >> 24) * sc;
  float f2 = (float)((int)(q.x <<  8) >> 24) * sc;
  float f3 = (float)((int)q.x >> 24) * sc;
  float f4 = (float)((int)(q.y << 24) >> 24) * sc;
  float f5 = (float)((int)(q.y << 16) >> 24) * sc;
  float f6 = (float)((int)(q.y <<  8) >> 24) * sc;
  float f7 = (float)((int)q.y >> 24) * sc;
  uint4 v = make_uint4(pack_bf16(f0, f1), pack_bf16(f2, f3),
                       pack_bf16(f4, f5), pack_bf16(f6, f7));
  return __builtin_bit_cast(short8, v);
}

// out = relu(bias + x@Wt0 + S1@Wt1 + S2@Wt2 + S3@Wt3), MFMA 16x16x32 bf16.
// x bf16; S1,S2,S3 int8 + per-node scale (dequantized in-register to A-frags).
__global__ __launch_bounds__(256) void gemm4_mfma(
    const uint* __restrict__ A0bf,
    const uchar* __restrict__ A1i8, const float* __restrict__ A1sc,
    const uchar* __restrict__ A2i8, const float* __restrict__ A2sc,
    const uchar* __restrict__ A3i8, const float* __restrict__ A3sc,
    const uint* __restrict__ wtT,   // [64][128] words (bf16 [64][256])
    const float* __restrict__ bias, float* __restrict__ out) {
  __shared__ uint WS[64 * 132];
  __shared__ float bias_s[64];
  for (int w = threadIdx.x; w < 8192; w += 256)
    WS[(w >> 7) * 132 + (w & 127)] = wtT[w];
  if (threadIdx.x < 64) bias_s[threadIdx.x] = bias[threadIdx.x];
  __syncthreads();

  const int lane = threadIdx.x & 63;
  const int wv = threadIdx.x >> 6;
  const int r0 = blockIdx.x * 64 + wv * 16;
  const int c16 = lane & 15;
  const int hi = lane >> 4;

  const int ar = r0 + c16;                         // A row for this lane
  const size_t arow_w = (size_t)ar * 32 + hi * 4;  // bf16 word offset
  const size_t arow_b = (size_t)ar * 64 + hi * 8;  // i8 byte offset
  const int nd = ar >> 2;
  const float sc1 = A1sc[nd];
  const float sc2 = A2sc[nd];
  const float sc3 = A3sc[nd];

  f32x4 acc[4] = {{0.f, 0.f, 0.f, 0.f}, {0.f, 0.f, 0.f, 0.f},
                  {0.f, 0.f, 0.f, 0.f}, {0.f, 0.f, 0.f, 0.f}};

#pragma unroll
  for (int ks = 0; ks < 8; ++ks) {
    short8 afrag;
    const int m = ks >> 1;
    if (m == 0) {
      uint4 av = *reinterpret_cast<const uint4*>(A0bf + arow_w + (ks & 1) * 16);
      afrag = __builtin_bit_cast(short8, av);
    } else if (m == 1) {
      uint2 qv = *reinterpret_cast<const uint2*>(A1i8 + arow_b + (ks & 1) * 32);
      afrag = dequant8(qv, sc1);
    } else if (m == 2) {
      uint2 qv = *reinterpret_cast<const uint2*>(A2i8 + arow_b + (ks & 1) * 32);
      afrag = dequant8(qv, sc2);
    } else {
      uint2 qv = *reinterpret_cast<const uint2*>(A3i8 + arow_b + (ks & 1) * 32);
      afrag = dequant8(qv, sc3);
    }
#pragma unroll
    for (int nt = 0; nt < 4; ++nt) {
      uint4 bv = *reinterpret_cast<const uint4*>(
          &WS[(nt * 16 + c16) * 132 + ks * 16 + hi * 4]);
      short8 bfrag = __builtin_bit_cast(short8, bv);
      acc[nt] = __builtin_amdgcn_mfma_f32_16x16x32_bf16(afrag, bfrag, acc[nt], 0, 0, 0);
    }
  }

  // C/D layout: col = lane&15, row = (lane>>4)*4 + i  [verified m89/m91]
#pragma unroll
  for (int nt = 0; nt < 4; ++nt) {
#pragma unroll
    for (int i = 0; i < 4; ++i) {
      int row = r0 + hi * 4 + i;
      int node = row >> 2, b = row & 3;
      int col = nt * 16 + c16;
      float v = acc[nt][i] + bias_s[col];
      out[(size_t)b * BN + (size_t)node * 64 + col] = fmaxf(v, 0.f);
    }
  }
}

extern "C" void kernel_launch(void* const* d_in, const int* in_sizes, int n_in,
                              void* d_out, int out_size, void* d_ws, size_t ws_size,
                              hipStream_t stream) {
  const float* x        = (const float*)d_in[0];
  const int*   lap_rows = (const int*)d_in[1];
  const int*   lap_cols = (const int*)d_in[2];
  const float* lap_vals = (const float*)d_in[3];
  const float* weights  = (const float*)d_in[4];  // [4][64][64]
  const float* bias     = (const float*)d_in[5];
  float* out = (float*)d_out;

  char* ws = (char*)d_ws;
  size_t off = 0;
  auto alloc = [&](size_t bytes) {
    void* p = ws + off;
    off += (bytes + 255) & ~(size_t)255;
    return p;
  };
  int*    gcounts     = (int*)alloc((size_t)NB * 4);
  int*    gcursor     = (int*)alloc((size_t)NB * 4);
  int*    bucket_base = (int*)alloc((size_t)(NB + 1) * 4);
  int*    row_start   = (int*)alloc((size_t)(N_NODES + 1) * 4);
  uint2*  pairs       = (uint2*)alloc((size_t)N_EDGES * 8);
  uint2*  staging     = (uint2*)alloc((size_t)N_EDGES * 8);
  ushort* wtT         = (ushort*)alloc((size_t)64 * 256 * 2);
  uint*   xb          = (uint*)alloc((size_t)N_NODES * 128 * 4);  // bf16 25.6MB
  uchar*  xi8         = (uchar*)alloc((size_t)N_NODES * 256);     // 12.8MB each
  uchar*  S1i         = (uchar*)alloc((size_t)N_NODES * 256);
  uchar*  S2i         = (uchar*)alloc((size_t)N_NODES * 256);
  uchar*  S3i         = (uchar*)alloc((size_t)N_NODES * 256);
  float*  xsc         = (float*)alloc((size_t)N_NODES * 4);
  float*  S1sc        = (float*)alloc((size_t)N_NODES * 4);
  float*  S2sc        = (float*)alloc((size_t)N_NODES * 4);
  float*  S3sc        = (float*)alloc((size_t)N_NODES * 4);
  (void)ws_size; (void)in_sizes; (void)n_in; (void)out_size;

  // Weight prep + x conversion + CSR build (counting sort)
  wprep_kernel<<<64, 256, 0, stream>>>(weights, wtT);
  cvt_kernel<<<N_NODES / 4, 256, 0, stream>>>(x, xb, (uint*)xi8, xsc);
  hipMemsetAsync(gcounts, 0, (size_t)NB * 4, stream);
  bucket_hist<<<SCT_BLOCKS, 1024, 0, stream>>>(lap_rows, gcounts);
  bucket_scan<<<1, 1024, 0, stream>>>(gcounts, bucket_base, gcursor);
  bucket_scatter<<<SCT_BLOCKS, 1024, 0, stream>>>(lap_rows, lap_cols, lap_vals,
                                                  gcursor, staging);
  bucket_finalize<<<NB, 256, 0, stream>>>(bucket_base, staging, pairs, row_start);

  const int spmm_blocks = N_NODES / 4;  // 12500, one wave per node row

  // S1 = L x ; S2 = L S1 ; S3 = L S2  (all i8 -> i8, per-node scales)
  spmm_s1<<<spmm_blocks, 256, 0, stream>>>(row_start, pairs, xi8, xsc, S1i, S1sc);
  spmm_s2<<<spmm_blocks, 256, 0, stream>>>(row_start, pairs, S1i, S1sc, S2i, S2sc);
  spmm_s3<<<spmm_blocks, 256, 0, stream>>>(row_start, pairs, S2i, S2sc, S3i, S3sc);
  // out = relu(bias + x@Wt0 + S1@Wt1 + S2@Wt2 + S3@Wt3)
  gemm4_mfma<<<ROWS_TOTAL / 64, 256, 0, stream>>>(xb, S1i, S1sc, S2i, S2sc,
                                                  S3i, S3sc, (const uint*)wtT,
                                                  bias, out);
}